// Round 2
// baseline (419.642 us; speedup 1.0000x reference)
//
#include <hip/hip_runtime.h>
#include <hip/hip_bf16.h>
#include <stdint.h>

// Problem constants
#define B_ 2
#define S_ 2048
#define D_ 1024
#define H_ 16
#define DH_ 64
#define FF_ 4096
#define M_ (B_*S_)   // 4096 tokens

typedef __bf16 bf16;
typedef __bf16 bf16x8 __attribute__((ext_vector_type(8)));
typedef float f32x4 __attribute__((ext_vector_type(4)));

// global -> LDS direct load, 16B per lane. LDS dest = wave-uniform base + lane*16.
__device__ __forceinline__ void gload_lds16(const void* g, void* l) {
  auto gp = reinterpret_cast<const __attribute__((address_space(1))) void*>(
      reinterpret_cast<uintptr_t>(g));
  auto lp = reinterpret_cast<__attribute__((address_space(3))) void*>(
      reinterpret_cast<uintptr_t>(l));
  __builtin_amdgcn_global_load_lds(gp, lp, 16, 0, 0);
}

// ---------------- prep kernels ----------------

__global__ __launch_bounds__(256) void cast_f32_bf16(
    const float* __restrict__ in, bf16* __restrict__ out, int n) {
  int i = (blockIdx.x * 256 + threadIdx.x) * 4;
  if (i < n) {
    float4 v = *(const float4*)(in + i);
    out[i+0] = (bf16)v.x; out[i+1] = (bf16)v.y;
    out[i+2] = (bf16)v.z; out[i+3] = (bf16)v.w;
  }
}

__global__ __launch_bounds__(256) void copy3(
    const float* __restrict__ a, const float* __restrict__ b,
    const float* __restrict__ c, float* __restrict__ out) {
  int i = blockIdx.x * 256 + threadIdx.x;   // 0..3071
  out[i] = i < 1024 ? a[i] : (i < 2048 ? b[i-1024] : c[i-2048]);
}

// in [K][N] f32 -> out [N][K] bf16
__global__ __launch_bounds__(256) void transpose_cast(
    const float* __restrict__ in, bf16* __restrict__ out, int K, int N) {
  __shared__ float t[32][33];
  int tx = threadIdx.x & 31, ty = threadIdx.x >> 5;  // ty 0..7
  int n0 = blockIdx.x * 32, k0 = blockIdx.y * 32;
#pragma unroll
  for (int i = 0; i < 4; i++)
    t[ty + i*8][tx] = in[(size_t)(k0 + ty + i*8) * N + n0 + tx];
  __syncthreads();
#pragma unroll
  for (int i = 0; i < 4; i++)
    out[(size_t)(n0 + ty + i*8) * K + k0 + tx] = (bf16)t[tx][ty + i*8];
}

// QKV [4096][3072] (V section) -> Vt [B*H][64][2048]
__global__ __launch_bounds__(256) void transpose_v(
    const bf16* __restrict__ QKV, bf16* __restrict__ Vt) {
  __shared__ bf16 t[64][66];   // stride 66 elems = 132B: conflict-free read
  int bh = blockIdx.x, s0 = blockIdx.y * 64;
  int b = bh >> 4, h = bh & 15;
  int w = threadIdx.x >> 6, l = threadIdx.x & 63;
#pragma unroll
  for (int i = 0; i < 16; i++) {
    int sr = w*16 + i;
    t[sr][l] = QKV[(size_t)(b*S_ + s0 + sr) * 3072 + 2*D_ + h*DH_ + l];
  }
  __syncthreads();
#pragma unroll
  for (int i = 0; i < 16; i++) {
    int dh = w*16 + i;
    Vt[((size_t)(bh*DH_ + dh)) * S_ + s0 + l] = t[l][dh];
  }
}

// ---------------- GEMM: C[M][N] = A[M][K] @ Bt[N][K]^T + bias ----------------
// m97 structure: 128x128 tile, BK=32, 4 waves (2x2), global_load_lds staging.
template<bool OUTF32, bool RELU>
__global__ __launch_bounds__(256) void gemm_bt(
    const bf16* __restrict__ A, const bf16* __restrict__ Bt,
    const float* __restrict__ bias, void* __restrict__ Cp,
    int M, int N, int K) {
  __shared__ bf16 As[128*32];
  __shared__ bf16 Bs[128*32];
  const int tid = threadIdx.x;
  const int w = tid >> 6, l = tid & 63;
  const int wm = w >> 1, wn = w & 1;
  const int r16 = l & 15, g = l >> 4;
  const int m0 = blockIdx.y * 128, n0 = blockIdx.x * 128;

  // staging: pass p covers rows p*64 + w*16 + (l>>2), 16B chunk (l&3)
  const int srow = w*16 + (l >> 2);
  const int acol8 = (l & 3) * 8;
  const bf16* ag = A + (size_t)(m0 + srow) * K + acol8;
  const bf16* bg = Bt + (size_t)(n0 + srow) * K + acol8;
  bf16* as_base = &As[(w*16) * 32];
  bf16* bs_base = &Bs[(w*16) * 32];

  f32x4 acc[4][4];
#pragma unroll
  for (int i = 0; i < 4; i++)
#pragma unroll
    for (int j = 0; j < 4; j++) acc[i][j] = (f32x4){0.f,0.f,0.f,0.f};

  for (int k0 = 0; k0 < K; k0 += 32) {
#pragma unroll
    for (int p = 0; p < 2; p++) {
      gload_lds16(ag + (size_t)(p*64) * K + k0, as_base + p*64*32);
      gload_lds16(bg + (size_t)(p*64) * K + k0, bs_base + p*64*32);
    }
    __syncthreads();
    bf16x8 af[4], bfr[4];
#pragma unroll
    for (int mi = 0; mi < 4; mi++)
      af[mi] = *(const bf16x8*)&As[(wm*64 + mi*16 + r16) * 32 + g*8];
#pragma unroll
    for (int ni = 0; ni < 4; ni++)
      bfr[ni] = *(const bf16x8*)&Bs[(wn*64 + ni*16 + r16) * 32 + g*8];
#pragma unroll
    for (int mi = 0; mi < 4; mi++)
#pragma unroll
      for (int ni = 0; ni < 4; ni++)
        acc[mi][ni] = __builtin_amdgcn_mfma_f32_16x16x32_bf16(
            af[mi], bfr[ni], acc[mi][ni], 0, 0, 0);
    __syncthreads();
  }

  float bvs[4];
#pragma unroll
  for (int ni = 0; ni < 4; ni++) bvs[ni] = bias[n0 + wn*64 + ni*16 + r16];
#pragma unroll
  for (int mi = 0; mi < 4; mi++)
#pragma unroll
    for (int ni = 0; ni < 4; ni++)
#pragma unroll
      for (int r = 0; r < 4; r++) {
        float v = acc[mi][ni][r] + bvs[ni];
        if (RELU) v = fmaxf(v, 0.f);
        size_t row = (size_t)(m0 + wm*64 + mi*16 + g*4 + r);
        size_t col = (size_t)(n0 + wn*64 + ni*16 + r16);
        if (OUTF32) ((float*)Cp)[row * N + col] = v;
        else        ((bf16*)Cp)[row * N + col] = (bf16)v;
      }
}

// ---------------- flash attention ----------------
// grid (B*H, S/64); 4 waves, wave w owns 16 q rows. KV tile = 32.
__global__ __launch_bounds__(256) void attn(
    const bf16* __restrict__ QKV, const bf16* __restrict__ Vt,
    const int* __restrict__ mask, bf16* __restrict__ AO) {
  __shared__ bf16 Ks[32*64];      // [kv][dh], XOR-swizzled (chunk ^= row&7)
  __shared__ bf16 Vs[64*32];      // [dh][kv], XOR-swizzled (chunk ^= row&3)
  __shared__ bf16 Ps[4][16*40];   // per-wave P, row stride 40 elems (80B)
  __shared__ float Mk[S_];

  const int bh = blockIdx.x, b = bh >> 4, h = bh & 15;
  const int q0 = blockIdx.y * 64;
  const int tid = threadIdx.x, w = tid >> 6, l = tid & 63;
  const int r16 = l & 15, g = l >> 4;

  for (int i = tid; i < S_; i += 256) Mk[i] = -10000.0f * (float)mask[b*S_ + i];

  // Q fragments (A operand): lane row = r16, k = kk*32 + g*8..+7
  bf16x8 qf[2];
  const size_t qrow = (size_t)(b*S_ + q0 + w*16 + r16);
#pragma unroll
  for (int kk = 0; kk < 2; kk++)
    qf[kk] = *(const bf16x8*)&QKV[qrow*3072 + h*64 + kk*32 + g*8];

  f32x4 po[4];
#pragma unroll
  for (int n = 0; n < 4; n++) po[n] = (f32x4){0.f,0.f,0.f,0.f};
  float mrun[4], lrun[4];
#pragma unroll
  for (int r = 0; r < 4; r++) { mrun[r] = -3.0e38f; lrun[r] = 0.f; }

  // staging addresses (pre-swizzled global source, linear LDS dest)
  const int krow = w*8 + (l >> 3);
  const int kch = (l & 7) ^ (krow & 7);
  const bf16* kg = QKV + ((size_t)(b*S_) + krow)*3072 + 1024 + h*64 + kch*8;
  bf16* ks_base = &Ks[w*8*64];
  const int vrow = w*16 + (l >> 2);
  const int vch = (l & 3) ^ (vrow & 3);
  const bf16* vg = Vt + ((size_t)(bh*64 + vrow))*S_ + vch*8;
  bf16* vs_base = &Vs[w*16*32];

  for (int kv0 = 0; kv0 < S_; kv0 += 32) {
    gload_lds16(kg + (size_t)kv0*3072, ks_base);
    gload_lds16(vg + kv0, vs_base);
    __syncthreads();

    // scores: 2 col-tiles x 2 k-steps
    float sv[2][4];
#pragma unroll
    for (int ct = 0; ct < 2; ct++) {
      f32x4 s = (f32x4){0.f,0.f,0.f,0.f};
#pragma unroll
      for (int kk = 0; kk < 2; kk++) {
        const int row = ct*16 + r16;
        bf16x8 kf = *(const bf16x8*)&Ks[row*64 + (((kk*4 + g) ^ (row & 7)))*8];
        s = __builtin_amdgcn_mfma_f32_16x16x32_bf16(qf[kk], kf, s, 0, 0, 0);
      }
      float madd = Mk[kv0 + ct*16 + r16];  // col = r16 = kv index
#pragma unroll
      for (int r = 0; r < 4; r++) sv[ct][r] = s[r]*0.125f + madd;
    }

    // online softmax per row (rows g*4+r; reduce across 16 lanes of group)
    float pr[2][4];
#pragma unroll
    for (int r = 0; r < 4; r++) {
      float tmax = fmaxf(sv[0][r], sv[1][r]);
#pragma unroll
      for (int off = 8; off >= 1; off >>= 1)
        tmax = fmaxf(tmax, __shfl_xor(tmax, off, 16));
      float mnew = fmaxf(mrun[r], tmax);
      float sc = __expf(mrun[r] - mnew);
      mrun[r] = mnew;
      float p0 = __expf(sv[0][r] - mnew);
      float p1 = __expf(sv[1][r] - mnew);
      pr[0][r] = p0; pr[1][r] = p1;
      float rs = p0 + p1;
#pragma unroll
      for (int off = 8; off >= 1; off >>= 1) rs += __shfl_xor(rs, off, 16);
      lrun[r] = lrun[r]*sc + rs;
#pragma unroll
      for (int n = 0; n < 4; n++) po[n][r] *= sc;
    }

    // P -> LDS (per-wave buffer), then PV
#pragma unroll
    for (int ct = 0; ct < 2; ct++)
#pragma unroll
      for (int r = 0; r < 4; r++)
        Ps[w][(g*4 + r)*40 + ct*16 + r16] = (bf16)pr[ct][r];
    asm volatile("s_waitcnt lgkmcnt(0)" ::: "memory");

    bf16x8 pa = *(const bf16x8*)&Ps[w][r16*40 + g*8];
#pragma unroll
    for (int n = 0; n < 4; n++) {
      const int row = n*16 + r16;
      bf16x8 vf = *(const bf16x8*)&Vs[row*32 + ((g ^ (row & 3)))*8];
      po[n] = __builtin_amdgcn_mfma_f32_16x16x32_bf16(pa, vf, po[n], 0, 0, 0);
    }
    __syncthreads();
  }

#pragma unroll
  for (int n = 0; n < 4; n++)
#pragma unroll
    for (int r = 0; r < 4; r++) {
      float v = po[n][r] / lrun[r];
      AO[(size_t)(b*S_ + q0 + w*16 + g*4 + r)*D_ + h*64 + n*16 + r16] = (bf16)v;
    }
}

// ---------------- fused residual + LayerNorm ----------------
template<bool WB>
__global__ __launch_bounds__(256) void ln_res(
    const float* __restrict__ x, const float* __restrict__ r,
    const float* __restrict__ sc, const float* __restrict__ bi,
    float* __restrict__ y, bf16* __restrict__ yb) {
  const int row = blockIdx.x, tid = threadIdx.x;
  const size_t base = (size_t)row * D_;
  float4 a  = ((const float4*)(x + base))[tid];
  float4 b4 = ((const float4*)(r + base))[tid];
  float v[4] = {a.x + b4.x, a.y + b4.y, a.z + b4.z, a.w + b4.w};
  float s  = v[0] + v[1] + v[2] + v[3];
  float ss = v[0]*v[0] + v[1]*v[1] + v[2]*v[2] + v[3]*v[3];
#pragma unroll
  for (int off = 32; off >= 1; off >>= 1) {
    s  += __shfl_xor(s, off, 64);
    ss += __shfl_xor(ss, off, 64);
  }
  __shared__ float red[8];
  const int wv = tid >> 6;
  if ((tid & 63) == 0) { red[wv] = s; red[4 + wv] = ss; }
  __syncthreads();
  s  = red[0] + red[1] + red[2] + red[3];
  ss = red[4] + red[5] + red[6] + red[7];
  const float mu  = s * (1.0f / D_);
  const float inv = rsqrtf(ss * (1.0f / D_) - mu*mu + 1e-6f);
  float4 scv = ((const float4*)sc)[tid];
  float4 biv = ((const float4*)bi)[tid];
  float o[4];
  o[0] = (v[0]-mu)*inv*scv.x + biv.x;
  o[1] = (v[1]-mu)*inv*scv.y + biv.y;
  o[2] = (v[2]-mu)*inv*scv.z + biv.z;
  o[3] = (v[3]-mu)*inv*scv.w + biv.w;
  ((float4*)(y + base))[tid] = make_float4(o[0], o[1], o[2], o[3]);
  if (WB) {
#pragma unroll
    for (int j = 0; j < 4; j++) yb[base + tid*4 + j] = (bf16)o[j];
  }
}

// ---------------- launch ----------------
extern "C" void kernel_launch(void* const* d_in, const int* in_sizes, int n_in,
                              void* d_out, int out_size, void* d_ws, size_t ws_size,
                              hipStream_t stream) {
  const float* X    = (const float*)d_in[0];
  const int*   mask = (const int*)d_in[1];
  const float* Wq   = (const float*)d_in[2];
  const float* bq   = (const float*)d_in[3];
  const float* Wk   = (const float*)d_in[4];
  const float* bk   = (const float*)d_in[5];
  const float* Wv   = (const float*)d_in[6];
  const float* bv   = (const float*)d_in[7];
  const float* Wo   = (const float*)d_in[8];
  const float* bo   = (const float*)d_in[9];
  const float* ln0s = (const float*)d_in[10];
  const float* ln0b = (const float*)d_in[11];
  const float* W1   = (const float*)d_in[12];
  const float* b1   = (const float*)d_in[13];
  const float* W2   = (const float*)d_in[14];
  const float* b2   = (const float*)d_in[15];
  const float* ln1s = (const float*)d_in[16];
  const float* ln1b = (const float*)d_in[17];
  float* out = (float*)d_out;

  // workspace layout (104 MB total), with phase-safe reuse:
  //  Xb (dead after QKV gemm) reused as AO; QKV+Vt reused as FF1; bqkv lives
  //  at the head of Proj (dead before Wo-gemm writes Proj).
  char* ws = (char*)d_ws;
  const size_t MB = 1024 * 1024;
  bf16*  Xb    = (bf16*)(ws + 0);        // 8MB
  bf16*  AO    = (bf16*)(ws + 0);        // reuse
  bf16*  Wqkvt = (bf16*)(ws + 8*MB);     // 6MB  [3072][1024]
  bf16*  Wot   = (bf16*)(ws + 14*MB);    // 2MB  [1024][1024]
  bf16*  W1t   = (bf16*)(ws + 16*MB);    // 8MB  [4096][1024]
  bf16*  W2t   = (bf16*)(ws + 24*MB);    // 8MB  [1024][4096]
  bf16*  QKV   = (bf16*)(ws + 32*MB);    // 24MB [4096][3072]
  bf16*  Vt    = (bf16*)(ws + 56*MB);    // 8MB  [32][64][2048]
  bf16*  FF1   = (bf16*)(ws + 32*MB);    // 32MB reuse [4096][4096]
  float* Proj  = (float*)(ws + 64*MB);   // 16MB (also FF2 out)
  float* bqkv  = (float*)(ws + 64*MB);   // 12KB, head of Proj (dead by Wo-gemm)
  float* X1    = (float*)(ws + 80*MB);   // 16MB
  bf16*  X1b   = (bf16*)(ws + 96*MB);    // 8MB

  cast_f32_bf16<<<(M_*D_)/1024, 256, 0, stream>>>(X, Xb, M_*D_);
  copy3<<<12, 256, 0, stream>>>(bq, bk, bv, bqkv);
  transpose_cast<<<dim3(D_/32, D_/32), 256, 0, stream>>>(Wq, Wqkvt, D_, D_);
  transpose_cast<<<dim3(D_/32, D_/32), 256, 0, stream>>>(Wk, Wqkvt + (size_t)1024*1024, D_, D_);
  transpose_cast<<<dim3(D_/32, D_/32), 256, 0, stream>>>(Wv, Wqkvt + (size_t)2048*1024, D_, D_);
  transpose_cast<<<dim3(D_/32, D_/32), 256, 0, stream>>>(Wo, Wot, D_, D_);
  transpose_cast<<<dim3(FF_/32, D_/32), 256, 0, stream>>>(W1, W1t, D_, FF_);
  transpose_cast<<<dim3(D_/32, FF_/32), 256, 0, stream>>>(W2, W2t, FF_, D_);

  gemm_bt<false,false><<<dim3(3072/128, M_/128), 256, 0, stream>>>(Xb, Wqkvt, bqkv, QKV, M_, 3072, D_);
  transpose_v<<<dim3(32, S_/64), 256, 0, stream>>>(QKV, Vt);
  attn<<<dim3(32, S_/64), 256, 0, stream>>>(QKV, Vt, mask, AO);
  gemm_bt<true,false><<<dim3(D_/128, M_/128), 256, 0, stream>>>(AO, Wot, bo, Proj, M_, D_, D_);
  ln_res<true><<<M_, 256, 0, stream>>>(X, Proj, ln0s, ln0b, X1, X1b);
  gemm_bt<false,true><<<dim3(FF_/128, M_/128), 256, 0, stream>>>(X1b, W1t, b1, FF1, M_, FF_, D_);
  gemm_bt<true,false><<<dim3(D_/128, M_/128), 256, 0, stream>>>(FF1, W2t, b2, Proj, M_, D_, FF_);
  ln_res<false><<<M_, 256, 0, stream>>>(X1, Proj, ln1s, ln1b, out, nullptr);
}

// Round 4
// 383.780 us; speedup vs baseline: 1.0934x; 1.0934x over previous
//
#include <hip/hip_runtime.h>
#include <hip/hip_bf16.h>
#include <stdint.h>

// Problem constants
#define B_ 2
#define S_ 2048
#define D_ 1024
#define H_ 16
#define DH_ 64
#define FF_ 4096
#define M_ (B_*S_)   // 4096 tokens

typedef __bf16 bf16;
typedef __bf16 bf16x8 __attribute__((ext_vector_type(8)));
typedef float f32x4 __attribute__((ext_vector_type(4)));

// global -> LDS direct load, 16B per lane. LDS dest = wave-uniform base + lane*16.
__device__ __forceinline__ void gload_lds16(const void* g, void* l) {
  auto gp = reinterpret_cast<const __attribute__((address_space(1))) void*>(
      reinterpret_cast<uintptr_t>(g));
  auto lp = reinterpret_cast<__attribute__((address_space(3))) void*>(
      reinterpret_cast<uintptr_t>(l));
  __builtin_amdgcn_global_load_lds(gp, lp, 16, 0, 0);
}

// ---------------- prep kernels ----------------

__global__ __launch_bounds__(256) void cast_f32_bf16(
    const float* __restrict__ in, bf16* __restrict__ out, int n) {
  int i = (blockIdx.x * 256 + threadIdx.x) * 4;
  if (i < n) {
    float4 v = *(const float4*)(in + i);
    out[i+0] = (bf16)v.x; out[i+1] = (bf16)v.y;
    out[i+2] = (bf16)v.z; out[i+3] = (bf16)v.w;
  }
}

__global__ __launch_bounds__(256) void copy3(
    const float* __restrict__ a, const float* __restrict__ b,
    const float* __restrict__ c, float* __restrict__ out) {
  int i = blockIdx.x * 256 + threadIdx.x;   // 0..3071
  out[i] = i < 1024 ? a[i] : (i < 2048 ? b[i-1024] : c[i-2048]);
}

// in [K][N] f32 -> out [N][K] bf16
__global__ __launch_bounds__(256) void transpose_cast(
    const float* __restrict__ in, bf16* __restrict__ out, int K, int N) {
  __shared__ float t[32][33];
  int tx = threadIdx.x & 31, ty = threadIdx.x >> 5;  // ty 0..7
  int n0 = blockIdx.x * 32, k0 = blockIdx.y * 32;
#pragma unroll
  for (int i = 0; i < 4; i++)
    t[ty + i*8][tx] = in[(size_t)(k0 + ty + i*8) * N + n0 + tx];
  __syncthreads();
#pragma unroll
  for (int i = 0; i < 4; i++)
    out[(size_t)(n0 + ty + i*8) * K + k0 + tx] = (bf16)t[tx][ty + i*8];
}

// QKV [4096][3072] (V section) -> Vt [B*H][64][2048]
__global__ __launch_bounds__(256) void transpose_v(
    const bf16* __restrict__ QKV, bf16* __restrict__ Vt) {
  __shared__ bf16 t[64][66];
  int bh = blockIdx.x, s0 = blockIdx.y * 64;
  int b = bh >> 4, h = bh & 15;
  int w = threadIdx.x >> 6, l = threadIdx.x & 63;
#pragma unroll
  for (int i = 0; i < 16; i++) {
    int sr = w*16 + i;
    t[sr][l] = QKV[(size_t)(b*S_ + s0 + sr) * 3072 + 2*D_ + h*DH_ + l];
  }
  __syncthreads();
#pragma unroll
  for (int i = 0; i < 16; i++) {
    int dh = w*16 + i;
    Vt[((size_t)(bh*DH_ + dh)) * S_ + s0 + l] = t[l][dh];
  }
}

// ---------------- GEMM: C[M][N] = A[M][K] @ Bt[N][K]^T + bias ----------------
// m97 structure: 128x128 tile, BK=32, 4 waves (2x2), global_load_lds staging.
// T1: bijective XCD-chunked blockIdx swizzle (all grids have nwg % 8 == 0).
template<bool OUTF32, bool RELU>
__global__ __launch_bounds__(256) void gemm_bt(
    const bf16* __restrict__ A, const bf16* __restrict__ Bt,
    const float* __restrict__ bias, void* __restrict__ Cp,
    int M, int N, int K) {
  __shared__ bf16 As[128*32];
  __shared__ bf16 Bs[128*32];
  const int tid = threadIdx.x;
  const int w = tid >> 6, l = tid & 63;
  const int wm = w >> 1, wn = w & 1;
  const int r16 = l & 15, g = l >> 4;

  // XCD swizzle: dispatch id -> XCD = id % 8; give each XCD a contiguous chunk
  const int gx = gridDim.x;
  const int nwg = gx * gridDim.y;
  const int lid = blockIdx.y * gx + blockIdx.x;
  const int swz = (lid & 7) * (nwg >> 3) + (lid >> 3);
  const int m0 = (swz / gx) * 128, n0 = (swz % gx) * 128;

  const int srow = w*16 + (l >> 2);
  const int acol8 = (l & 3) * 8;
  const bf16* ag = A + (size_t)(m0 + srow) * K + acol8;
  const bf16* bg = Bt + (size_t)(n0 + srow) * K + acol8;
  bf16* as_base = &As[(w*16) * 32];
  bf16* bs_base = &Bs[(w*16) * 32];

  f32x4 acc[4][4];
#pragma unroll
  for (int i = 0; i < 4; i++)
#pragma unroll
    for (int j = 0; j < 4; j++) acc[i][j] = (f32x4){0.f,0.f,0.f,0.f};

  for (int k0 = 0; k0 < K; k0 += 32) {
#pragma unroll
    for (int p = 0; p < 2; p++) {
      gload_lds16(ag + (size_t)(p*64) * K + k0, as_base + p*64*32);
      gload_lds16(bg + (size_t)(p*64) * K + k0, bs_base + p*64*32);
    }
    __syncthreads();
    bf16x8 af[4], bfr[4];
#pragma unroll
    for (int mi = 0; mi < 4; mi++)
      af[mi] = *(const bf16x8*)&As[(wm*64 + mi*16 + r16) * 32 + g*8];
#pragma unroll
    for (int ni = 0; ni < 4; ni++)
      bfr[ni] = *(const bf16x8*)&Bs[(wn*64 + ni*16 + r16) * 32 + g*8];
#pragma unroll
    for (int mi = 0; mi < 4; mi++)
#pragma unroll
      for (int ni = 0; ni < 4; ni++)
        acc[mi][ni] = __builtin_amdgcn_mfma_f32_16x16x32_bf16(
            af[mi], bfr[ni], acc[mi][ni], 0, 0, 0);
    __syncthreads();
  }

  float bvs[4];
#pragma unroll
  for (int ni = 0; ni < 4; ni++) bvs[ni] = bias[n0 + wn*64 + ni*16 + r16];
#pragma unroll
  for (int mi = 0; mi < 4; mi++)
#pragma unroll
    for (int ni = 0; ni < 4; ni++)
#pragma unroll
      for (int r = 0; r < 4; r++) {
        float v = acc[mi][ni][r] + bvs[ni];
        if (RELU) v = fmaxf(v, 0.f);
        size_t row = (size_t)(m0 + wm*64 + mi*16 + g*4 + r);
        size_t col = (size_t)(n0 + wn*64 + ni*16 + r16);
        if (OUTF32) ((float*)Cp)[row * N + col] = v;
        else        ((bf16*)Cp)[row * N + col] = (bf16)v;
      }
}

// ---------------- flash attention ----------------
// grid (B*H, S/64); 4 waves, wave w owns 16 q rows. KVBLK=64, double-buffered
// K/V staging with counted vmcnt + raw barriers (loads in flight across bar).
__global__ __launch_bounds__(256) void attn(
    const bf16* __restrict__ QKV, const bf16* __restrict__ Vt,
    const int* __restrict__ mask, bf16* __restrict__ AO) {
  __shared__ bf16 Ks[2][64*64];   // [kv][dh], chunk ^= (kv&7), 16KB
  __shared__ bf16 Vs[2][64*64];   // [dh][kv], chunk ^= (dh&7), 16KB
  __shared__ bf16 Ps[4][16*72];   // per-wave P, row stride 72 elems (144B)
  __shared__ float Mk[S_];

  const int bh = blockIdx.x, b = bh >> 4, h = bh & 15;
  const int q0 = blockIdx.y * 64;
  const int tid = threadIdx.x, w = tid >> 6, l = tid & 63;
  const int r16 = l & 15, g = l >> 4;

  // Q fragments (A operand): lane row = r16 (q), k = kk*32 + g*8..+7
  bf16x8 qf[2];
  const size_t qrow = (size_t)(b*S_ + q0 + w*16 + r16);
#pragma unroll
  for (int kk = 0; kk < 2; kk++)
    qf[kk] = *(const bf16x8*)&QKV[qrow*3072 + h*64 + kk*32 + g*8];

  for (int i = tid; i < S_; i += 256) Mk[i] = -10000.0f * (float)mask[b*S_ + i];
  // ensure Mk visible to all waves at the first raw barrier
  asm volatile("s_waitcnt lgkmcnt(0)" ::: "memory");

  // staging source addrs (pre-swizzled global source, linear LDS dest).
  // pass p covers rows p*32 + w*8 + (l>>3), chunk l&7; swizzle = (l&7)^(l>>3)
  // (row&7 == l>>3 since w*8, p*32 are multiples of 8).
  const int srow = w*8 + (l >> 3);
  const int sch  = (l & 7) ^ (l >> 3);
  const bf16* kg = QKV + ((size_t)(b*S_) + srow)*3072 + 1024 + h*64 + sch*8;
  const bf16* vg = Vt + ((size_t)(bh*64 + srow))*S_ + sch*8;

  f32x4 po[4];
#pragma unroll
  for (int n = 0; n < 4; n++) po[n] = (f32x4){0.f,0.f,0.f,0.f};
  float mrun[4], lrun[4];
#pragma unroll
  for (int r = 0; r < 4; r++) { mrun[r] = -1.0e30f; lrun[r] = 0.f; }

  // prologue: stage tile 0 into buf 0 (4 gloads/lane)
#pragma unroll
  for (int p = 0; p < 2; p++) {
    gload_lds16(kg + (size_t)(p*32)*3072, &Ks[0][(p*256 + w*64)*8]);
    gload_lds16(vg + (size_t)(p*32)*S_,   &Vs[0][(p*256 + w*64)*8]);
  }

  int cur = 0;
  for (int it = 0; it < S_/64; ++it) {
    const int kv0 = it * 64;
    if (it + 1 < S_/64) {
      // issue next tile (4 gloads), then drain current tile only: vmcnt(4)
#pragma unroll
      for (int p = 0; p < 2; p++) {
        gload_lds16(kg + (size_t)(kv0 + 64 + p*32)*3072, &Ks[cur^1][(p*256 + w*64)*8]);
        gload_lds16(vg + (size_t)(p*32)*S_ + (kv0 + 64), &Vs[cur^1][(p*256 + w*64)*8]);
      }
      asm volatile("s_waitcnt vmcnt(4)" ::: "memory");
    } else {
      asm volatile("s_waitcnt vmcnt(0)" ::: "memory");
    }
    __builtin_amdgcn_s_barrier();
    asm volatile("" ::: "memory");

    // ---- QK^T: 4 col-tiles x 2 k-steps ----
    float sv[4][4];
    __builtin_amdgcn_s_setprio(1);
#pragma unroll
    for (int ct = 0; ct < 4; ct++) {
      f32x4 s = (f32x4){0.f,0.f,0.f,0.f};
#pragma unroll
      for (int kk = 0; kk < 2; kk++) {
        const int row = ct*16 + r16;
        bf16x8 kf = *(const bf16x8*)&Ks[cur][row*64 + ((kk*4 + g) ^ (row & 7))*8];
        s = __builtin_amdgcn_mfma_f32_16x16x32_bf16(qf[kk], kf, s, 0, 0, 0);
      }
      float madd = Mk[kv0 + ct*16 + r16];   // col = r16 = kv index
#pragma unroll
      for (int r = 0; r < 4; r++) sv[ct][r] = s[r]*0.125f + madd;
    }
    __builtin_amdgcn_s_setprio(0);

    // ---- online softmax (rows q = g*4+r; reduce over 16 lanes = kv) ----
    float tmax[4];
#pragma unroll
    for (int r = 0; r < 4; r++) {
      float t = fmaxf(fmaxf(sv[0][r], sv[1][r]), fmaxf(sv[2][r], sv[3][r]));
#pragma unroll
      for (int off = 8; off >= 1; off >>= 1) t = fmaxf(t, __shfl_xor(t, off, 16));
      tmax[r] = t;
    }
    // T13 defer-max: skip rescale unless some row's max grew by > 8
    bool grow = (tmax[0] > mrun[0] + 8.f) | (tmax[1] > mrun[1] + 8.f) |
                (tmax[2] > mrun[2] + 8.f) | (tmax[3] > mrun[3] + 8.f);
    if (__any(grow)) {
#pragma unroll
      for (int r = 0; r < 4; r++) {
        float mnew = fmaxf(mrun[r], tmax[r]);
        float sc = __expf(mrun[r] - mnew);
        mrun[r] = mnew;
        lrun[r] *= sc;
#pragma unroll
        for (int n = 0; n < 4; n++) po[n][r] *= sc;
      }
    }
    float pr[4][4];
#pragma unroll
    for (int r = 0; r < 4; r++) {
      float rs = 0.f;
#pragma unroll
      for (int ct = 0; ct < 4; ct++) {
        pr[ct][r] = __expf(sv[ct][r] - mrun[r]);
        rs += pr[ct][r];
      }
#pragma unroll
      for (int off = 8; off >= 1; off >>= 1) rs += __shfl_xor(rs, off, 16);
      lrun[r] += rs;
    }

    // ---- P -> per-wave LDS, then PV ----
#pragma unroll
    for (int ct = 0; ct < 4; ct++)
#pragma unroll
      for (int r = 0; r < 4; r++)
        Ps[w][(g*4 + r)*72 + ct*16 + r16] = (bf16)pr[ct][r];
    asm volatile("s_waitcnt lgkmcnt(0)" ::: "memory");

    __builtin_amdgcn_s_setprio(1);
#pragma unroll
    for (int kk = 0; kk < 2; kk++) {
      bf16x8 pa = *(const bf16x8*)&Ps[w][r16*72 + kk*32 + g*8];
#pragma unroll
      for (int n = 0; n < 4; n++) {
        const int row = n*16 + r16;
        bf16x8 vf = *(const bf16x8*)&Vs[cur][row*64 + ((kk*4 + g) ^ (row & 7))*8];
        po[n] = __builtin_amdgcn_mfma_f32_16x16x32_bf16(pa, vf, po[n], 0, 0, 0);
      }
    }
    __builtin_amdgcn_s_setprio(0);

    __builtin_amdgcn_s_barrier();
    asm volatile("" ::: "memory");
    cur ^= 1;
  }

#pragma unroll
  for (int n = 0; n < 4; n++)
#pragma unroll
    for (int r = 0; r < 4; r++) {
      float v = po[n][r] / lrun[r];
      AO[(size_t)(b*S_ + q0 + w*16 + g*4 + r)*D_ + h*64 + n*16 + r16] = (bf16)v;
    }
}

// ---------------- fused residual + LayerNorm ----------------
template<bool WB>
__global__ __launch_bounds__(256) void ln_res(
    const float* __restrict__ x, const float* __restrict__ r,
    const float* __restrict__ sc, const float* __restrict__ bi,
    float* __restrict__ y, bf16* __restrict__ yb) {
  const int row = blockIdx.x, tid = threadIdx.x;
  const size_t base = (size_t)row * D_;
  float4 a  = ((const float4*)(x + base))[tid];
  float4 b4 = ((const float4*)(r + base))[tid];
  float v[4] = {a.x + b4.x, a.y + b4.y, a.z + b4.z, a.w + b4.w};
  float s  = v[0] + v[1] + v[2] + v[3];
  float ss = v[0]*v[0] + v[1]*v[1] + v[2]*v[2] + v[3]*v[3];
#pragma unroll
  for (int off = 32; off >= 1; off >>= 1) {
    s  += __shfl_xor(s, off, 64);
    ss += __shfl_xor(ss, off, 64);
  }
  __shared__ float red[8];
  const int wv = tid >> 6;
  if ((tid & 63) == 0) { red[wv] = s; red[4 + wv] = ss; }
  __syncthreads();
  s  = red[0] + red[1] + red[2] + red[3];
  ss = red[4] + red[5] + red[6] + red[7];
  const float mu  = s * (1.0f / D_);
  const float inv = rsqrtf(ss * (1.0f / D_) - mu*mu + 1e-6f);
  float4 scv = ((const float4*)sc)[tid];
  float4 biv = ((const float4*)bi)[tid];
  float o[4];
  o[0] = (v[0]-mu)*inv*scv.x + biv.x;
  o[1] = (v[1]-mu)*inv*scv.y + biv.y;
  o[2] = (v[2]-mu)*inv*scv.z + biv.z;
  o[3] = (v[3]-mu)*inv*scv.w + biv.w;
  ((float4*)(y + base))[tid] = make_float4(o[0], o[1], o[2], o[3]);
  if (WB) {
#pragma unroll
    for (int j = 0; j < 4; j++) yb[base + tid*4 + j] = (bf16)o[j];
  }
}

// ---------------- launch ----------------
extern "C" void kernel_launch(void* const* d_in, const int* in_sizes, int n_in,
                              void* d_out, int out_size, void* d_ws, size_t ws_size,
                              hipStream_t stream) {
  const float* X    = (const float*)d_in[0];
  const int*   mask = (const int*)d_in[1];
  const float* Wq   = (const float*)d_in[2];
  const float* bq   = (const float*)d_in[3];
  const float* Wk   = (const float*)d_in[4];
  const float* bk   = (const float*)d_in[5];
  const float* Wv   = (const float*)d_in[6];
  const float* bv   = (const float*)d_in[7];
  const float* Wo   = (const float*)d_in[8];
  const float* bo   = (const float*)d_in[9];
  const float* ln0s = (const float*)d_in[10];
  const float* ln0b = (const float*)d_in[11];
  const float* W1   = (const float*)d_in[12];
  const float* b1   = (const float*)d_in[13];
  const float* W2   = (const float*)d_in[14];
  const float* b2   = (const float*)d_in[15];
  const float* ln1s = (const float*)d_in[16];
  const float* ln1b = (const float*)d_in[17];
  float* out = (float*)d_out;

  char* ws = (char*)d_ws;
  const size_t MB = 1024 * 1024;
  bf16*  Xb    = (bf16*)(ws + 0);        // 8MB
  bf16*  AO    = (bf16*)(ws + 0);        // reuse (Xb dead after QKV gemm)
  bf16*  Wqkvt = (bf16*)(ws + 8*MB);     // 6MB  [3072][1024]
  bf16*  Wot   = (bf16*)(ws + 14*MB);    // 2MB  [1024][1024]
  bf16*  W1t   = (bf16*)(ws + 16*MB);    // 8MB  [4096][1024]
  bf16*  W2t   = (bf16*)(ws + 24*MB);    // 8MB  [1024][4096]
  bf16*  QKV   = (bf16*)(ws + 32*MB);    // 24MB [4096][3072]
  bf16*  Vt    = (bf16*)(ws + 56*MB);    // 8MB  [32][64][2048]
  bf16*  FF1   = (bf16*)(ws + 32*MB);    // 32MB reuse [4096][4096]
  float* Proj  = (float*)(ws + 64*MB);   // 16MB (also FF2 out)
  float* bqkv  = (float*)(ws + 64*MB);   // 12KB, head of Proj (dead by Wo-gemm)
  float* X1    = (float*)(ws + 80*MB);   // 16MB
  bf16*  X1b   = (bf16*)(ws + 96*MB);    // 8MB

  cast_f32_bf16<<<(M_*D_)/1024, 256, 0, stream>>>(X, Xb, M_*D_);
  copy3<<<12, 256, 0, stream>>>(bq, bk, bv, bqkv);
  transpose_cast<<<dim3(D_/32, D_/32), 256, 0, stream>>>(Wq, Wqkvt, D_, D_);
  transpose_cast<<<dim3(D_/32, D_/32), 256, 0, stream>>>(Wk, Wqkvt + (size_t)1024*1024, D_, D_);
  transpose_cast<<<dim3(D_/32, D_/32), 256, 0, stream>>>(Wv, Wqkvt + (size_t)2048*1024, D_, D_);
  transpose_cast<<<dim3(D_/32, D_/32), 256, 0, stream>>>(Wo, Wot, D_, D_);
  transpose_cast<<<dim3(FF_/32, D_/32), 256, 0, stream>>>(W1, W1t, D_, FF_);
  transpose_cast<<<dim3(D_/32, FF_/32), 256, 0, stream>>>(W2, W2t, FF_, D_);

  gemm_bt<false,false><<<dim3(3072/128, M_/128), 256, 0, stream>>>(Xb, Wqkvt, bqkv, QKV, M_, 3072, D_);
  transpose_v<<<dim3(32, S_/64), 256, 0, stream>>>(QKV, Vt);
  attn<<<dim3(32, S_/64), 256, 0, stream>>>(QKV, Vt, mask, AO);
  gemm_bt<true,false><<<dim3(D_/128, M_/128), 256, 0, stream>>>(AO, Wot, bo, Proj, M_, D_, D_);
  ln_res<true><<<M_, 256, 0, stream>>>(X, Proj, ln0s, ln0b, X1, X1b);
  gemm_bt<false,true><<<dim3(FF_/128, M_/128), 256, 0, stream>>>(X1b, W1t, b1, FF1, M_, FF_, D_);
  gemm_bt<true,false><<<dim3(D_/128, M_/128), 256, 0, stream>>>(FF1, W2t, b2, Proj, M_, D_, FF_);
  ln_res<false><<<M_, 256, 0, stream>>>(X1, Proj, ln1s, ln1b, out, nullptr);
}

// Round 5
// 347.281 us; speedup vs baseline: 1.2084x; 1.1051x over previous
//
#include <hip/hip_runtime.h>
#include <hip/hip_bf16.h>
#include <stdint.h>

// Problem constants
#define B_ 2
#define S_ 2048
#define D_ 1024
#define H_ 16
#define DH_ 64
#define FF_ 4096
#define M_ (B_*S_)   // 4096 tokens

typedef __bf16 bf16;
typedef __bf16 bf16x8 __attribute__((ext_vector_type(8)));
typedef float f32x4 __attribute__((ext_vector_type(4)));

// global -> LDS direct load, 16B per lane. LDS dest = wave-uniform base + lane*16.
__device__ __forceinline__ void gload_lds16(const void* g, void* l) {
  auto gp = reinterpret_cast<const __attribute__((address_space(1))) void*>(
      reinterpret_cast<uintptr_t>(g));
  auto lp = reinterpret_cast<__attribute__((address_space(3))) void*>(
      reinterpret_cast<uintptr_t>(l));
  __builtin_amdgcn_global_load_lds(gp, lp, 16, 0, 0);
}

// ---------------- prep kernels ----------------

__global__ __launch_bounds__(256) void cast_f32_bf16(
    const float* __restrict__ in, bf16* __restrict__ out, int n) {
  int i = (blockIdx.x * 256 + threadIdx.x) * 4;
  if (i < n) {
    float4 v = *(const float4*)(in + i);
    out[i+0] = (bf16)v.x; out[i+1] = (bf16)v.y;
    out[i+2] = (bf16)v.z; out[i+3] = (bf16)v.w;
  }
}

__global__ __launch_bounds__(256) void copy3(
    const float* __restrict__ a, const float* __restrict__ b,
    const float* __restrict__ c, float* __restrict__ out) {
  int i = blockIdx.x * 256 + threadIdx.x;   // 0..3071
  out[i] = i < 1024 ? a[i] : (i < 2048 ? b[i-1024] : c[i-2048]);
}

// in [K][N] f32 -> out [N][K] bf16
__global__ __launch_bounds__(256) void transpose_cast(
    const float* __restrict__ in, bf16* __restrict__ out, int K, int N) {
  __shared__ float t[32][33];
  int tx = threadIdx.x & 31, ty = threadIdx.x >> 5;  // ty 0..7
  int n0 = blockIdx.x * 32, k0 = blockIdx.y * 32;
#pragma unroll
  for (int i = 0; i < 4; i++)
    t[ty + i*8][tx] = in[(size_t)(k0 + ty + i*8) * N + n0 + tx];
  __syncthreads();
#pragma unroll
  for (int i = 0; i < 4; i++)
    out[(size_t)(n0 + ty + i*8) * K + k0 + tx] = (bf16)t[tx][ty + i*8];
}

// QKV [4096][3072] (V section) -> Vt [B*H][64][2048]
__global__ __launch_bounds__(256) void transpose_v(
    const bf16* __restrict__ QKV, bf16* __restrict__ Vt) {
  __shared__ bf16 t[64][66];
  int bh = blockIdx.x, s0 = blockIdx.y * 64;
  int b = bh >> 4, h = bh & 15;
  int w = threadIdx.x >> 6, l = threadIdx.x & 63;
#pragma unroll
  for (int i = 0; i < 16; i++) {
    int sr = w*16 + i;
    t[sr][l] = QKV[(size_t)(b*S_ + s0 + sr) * 3072 + 2*D_ + h*DH_ + l];
  }
  __syncthreads();
#pragma unroll
  for (int i = 0; i < 16; i++) {
    int dh = w*16 + i;
    Vt[((size_t)(bh*DH_ + dh)) * S_ + s0 + l] = t[l][dh];
  }
}

// ---------------- GEMM: C[M][N] = A[M][K] @ Bt[N][K]^T + bias ----------------
// m97 structure: 128x128 tile, BK=32, 4 waves (2x2), global_load_lds staging.
// T1: bijective XCD-chunked blockIdx swizzle (all grids have nwg % 8 == 0).
template<bool OUTF32, bool RELU>
__global__ __launch_bounds__(256) void gemm_bt(
    const bf16* __restrict__ A, const bf16* __restrict__ Bt,
    const float* __restrict__ bias, void* __restrict__ Cp,
    int M, int N, int K) {
  __shared__ bf16 As[128*32];
  __shared__ bf16 Bs[128*32];
  const int tid = threadIdx.x;
  const int w = tid >> 6, l = tid & 63;
  const int wm = w >> 1, wn = w & 1;
  const int r16 = l & 15, g = l >> 4;

  // XCD swizzle: dispatch id -> XCD = id % 8; give each XCD a contiguous chunk
  const int gx = gridDim.x;
  const int nwg = gx * gridDim.y;
  const int lid = blockIdx.y * gx + blockIdx.x;
  const int swz = (lid & 7) * (nwg >> 3) + (lid >> 3);
  const int m0 = (swz / gx) * 128, n0 = (swz % gx) * 128;

  const int srow = w*16 + (l >> 2);
  const int acol8 = (l & 3) * 8;
  const bf16* ag = A + (size_t)(m0 + srow) * K + acol8;
  const bf16* bg = Bt + (size_t)(n0 + srow) * K + acol8;
  bf16* as_base = &As[(w*16) * 32];
  bf16* bs_base = &Bs[(w*16) * 32];

  f32x4 acc[4][4];
#pragma unroll
  for (int i = 0; i < 4; i++)
#pragma unroll
    for (int j = 0; j < 4; j++) acc[i][j] = (f32x4){0.f,0.f,0.f,0.f};

  for (int k0 = 0; k0 < K; k0 += 32) {
#pragma unroll
    for (int p = 0; p < 2; p++) {
      gload_lds16(ag + (size_t)(p*64) * K + k0, as_base + p*64*32);
      gload_lds16(bg + (size_t)(p*64) * K + k0, bs_base + p*64*32);
    }
    __syncthreads();
    bf16x8 af[4], bfr[4];
#pragma unroll
    for (int mi = 0; mi < 4; mi++)
      af[mi] = *(const bf16x8*)&As[(wm*64 + mi*16 + r16) * 32 + g*8];
#pragma unroll
    for (int ni = 0; ni < 4; ni++)
      bfr[ni] = *(const bf16x8*)&Bs[(wn*64 + ni*16 + r16) * 32 + g*8];
#pragma unroll
    for (int mi = 0; mi < 4; mi++)
#pragma unroll
      for (int ni = 0; ni < 4; ni++)
        acc[mi][ni] = __builtin_amdgcn_mfma_f32_16x16x32_bf16(
            af[mi], bfr[ni], acc[mi][ni], 0, 0, 0);
    __syncthreads();
  }

  float bvs[4];
#pragma unroll
  for (int ni = 0; ni < 4; ni++) bvs[ni] = bias[n0 + wn*64 + ni*16 + r16];
#pragma unroll
  for (int mi = 0; mi < 4; mi++)
#pragma unroll
    for (int ni = 0; ni < 4; ni++)
#pragma unroll
      for (int r = 0; r < 4; r++) {
        float v = acc[mi][ni][r] + bvs[ni];
        if (RELU) v = fmaxf(v, 0.f);
        size_t row = (size_t)(m0 + wm*64 + mi*16 + g*4 + r);
        size_t col = (size_t)(n0 + wn*64 + ni*16 + r16);
        if (OUTF32) ((float*)Cp)[row * N + col] = v;
        else        ((bf16*)Cp)[row * N + col] = (bf16)v;
      }
}

// ---------------- flash attention ----------------
// grid (B*H, S/64); 4 waves, wave w owns 16 q rows. KVBLK=64, double-buffered
// K/V staging with counted vmcnt + raw barriers (loads in flight across bar).
// Softmax: lane-local defer-max (THR=8) + per-lane deferred sum -> zero
// cross-lane ops per iteration in steady state.
__global__ __launch_bounds__(256) void attn(
    const bf16* __restrict__ QKV, const bf16* __restrict__ Vt,
    const int* __restrict__ mask, bf16* __restrict__ AO) {
  __shared__ bf16 Ks[2][64*64];   // [kv][dh], chunk ^= (kv&7), 16KB
  __shared__ bf16 Vs[2][64*64];   // [dh][kv], chunk ^= (dh&7), 16KB
  __shared__ bf16 Ps[4][16*72];   // per-wave P, row stride 72 elems (144B)
  __shared__ float Mk[S_];

  const int bh = blockIdx.x, b = bh >> 4, h = bh & 15;
  const int q0 = blockIdx.y * 64;
  const int tid = threadIdx.x, w = tid >> 6, l = tid & 63;
  const int r16 = l & 15, g = l >> 4;

  // Q fragments (A operand): lane row = r16 (q), k = kk*32 + g*8..+7
  bf16x8 qf[2];
  const size_t qrow = (size_t)(b*S_ + q0 + w*16 + r16);
#pragma unroll
  for (int kk = 0; kk < 2; kk++)
    qf[kk] = *(const bf16x8*)&QKV[qrow*3072 + h*64 + kk*32 + g*8];

  for (int i = tid; i < S_; i += 256) Mk[i] = -10000.0f * (float)mask[b*S_ + i];
  // ensure Mk (this wave's ds_writes) drained before the first barrier
  asm volatile("s_waitcnt lgkmcnt(0)" ::: "memory");

  // staging source addrs (pre-swizzled global source, linear LDS dest).
  const int srow = w*8 + (l >> 3);
  const int sch  = (l & 7) ^ (l >> 3);
  const bf16* kg = QKV + ((size_t)(b*S_) + srow)*3072 + 1024 + h*64 + sch*8;
  const bf16* vg = Vt + ((size_t)(bh*64 + srow))*S_ + sch*8;

  f32x4 po[4];
#pragma unroll
  for (int n = 0; n < 4; n++) po[n] = (f32x4){0.f,0.f,0.f,0.f};
  float mrun[4], lsum[4];
#pragma unroll
  for (int r = 0; r < 4; r++) { mrun[r] = -1.0e30f; lsum[r] = 0.f; }

  // prologue: stage tile 0 into buf 0 (4 gloads/lane)
#pragma unroll
  for (int p = 0; p < 2; p++) {
    gload_lds16(kg + (size_t)(p*32)*3072, &Ks[0][(p*256 + w*64)*8]);
    gload_lds16(vg + (size_t)(p*32)*S_,   &Vs[0][(p*256 + w*64)*8]);
  }

  int cur = 0;
  for (int it = 0; it < S_/64; ++it) {
    const int kv0 = it * 64;
    if (it + 1 < S_/64) {
      // issue next tile (4 gloads), then drain current tile only: vmcnt(4)
#pragma unroll
      for (int p = 0; p < 2; p++) {
        gload_lds16(kg + (size_t)(kv0 + 64 + p*32)*3072, &Ks[cur^1][(p*256 + w*64)*8]);
        gload_lds16(vg + (size_t)(p*32)*S_ + (kv0 + 64), &Vs[cur^1][(p*256 + w*64)*8]);
      }
      asm volatile("s_waitcnt vmcnt(4)" ::: "memory");
    } else {
      asm volatile("s_waitcnt vmcnt(0)" ::: "memory");
    }
    __builtin_amdgcn_s_barrier();
    asm volatile("" ::: "memory");

    // ---- QK^T: 4 col-tiles x 2 k-steps ----
    float sv[4][4];
    __builtin_amdgcn_s_setprio(1);
#pragma unroll
    for (int ct = 0; ct < 4; ct++) {
      f32x4 s = (f32x4){0.f,0.f,0.f,0.f};
#pragma unroll
      for (int kk = 0; kk < 2; kk++) {
        const int row = ct*16 + r16;
        bf16x8 kf = *(const bf16x8*)&Ks[cur][row*64 + ((kk*4 + g) ^ (row & 7))*8];
        s = __builtin_amdgcn_mfma_f32_16x16x32_bf16(qf[kk], kf, s, 0, 0, 0);
      }
      float madd = Mk[kv0 + ct*16 + r16];   // col = r16 = kv index
#pragma unroll
      for (int r = 0; r < 4; r++) sv[ct][r] = s[r]*0.125f + madd;
    }
    __builtin_amdgcn_s_setprio(0);

    // ---- lane-local softmax: no cross-lane ops in steady state ----
    float lmax[4];
#pragma unroll
    for (int r = 0; r < 4; r++)
      lmax[r] = fmaxf(fmaxf(sv[0][r], sv[1][r]), fmaxf(sv[2][r], sv[3][r]));
    // rescale only if some lane's local max grew past mrun + 8 (THR=8)
    bool grow = (lmax[0] > mrun[0] + 8.f) | (lmax[1] > mrun[1] + 8.f) |
                (lmax[2] > mrun[2] + 8.f) | (lmax[3] > mrun[3] + 8.f);
    if (__any(grow)) {
#pragma unroll
      for (int r = 0; r < 4; r++) {
        float t = lmax[r];
#pragma unroll
        for (int off = 8; off >= 1; off >>= 1) t = fmaxf(t, __shfl_xor(t, off, 16));
        float mnew = fmaxf(mrun[r], t);
        float sc = __expf(mrun[r] - mnew);
        mrun[r] = mnew;
        lsum[r] *= sc;            // per-lane partial sum: rescale is linear
#pragma unroll
        for (int n = 0; n < 4; n++) po[n][r] *= sc;
      }
    }
    float pr[4][4];
#pragma unroll
    for (int r = 0; r < 4; r++) {
#pragma unroll
      for (int ct = 0; ct < 4; ct++)
        pr[ct][r] = __expf(sv[ct][r] - mrun[r]);   // bounded by e^8
      lsum[r] += (pr[0][r] + pr[1][r]) + (pr[2][r] + pr[3][r]);
    }

    // ---- P -> per-wave LDS, then PV ----
#pragma unroll
    for (int ct = 0; ct < 4; ct++)
#pragma unroll
      for (int r = 0; r < 4; r++)
        Ps[w][(g*4 + r)*72 + ct*16 + r16] = (bf16)pr[ct][r];
    asm volatile("s_waitcnt lgkmcnt(0)" ::: "memory");

    __builtin_amdgcn_s_setprio(1);
#pragma unroll
    for (int kk = 0; kk < 2; kk++) {
      bf16x8 pa = *(const bf16x8*)&Ps[w][r16*72 + kk*32 + g*8];
#pragma unroll
      for (int n = 0; n < 4; n++) {
        const int row = n*16 + r16;
        bf16x8 vf = *(const bf16x8*)&Vs[cur][row*64 + ((kk*4 + g) ^ (row & 7))*8];
        po[n] = __builtin_amdgcn_mfma_f32_16x16x32_bf16(pa, vf, po[n], 0, 0, 0);
      }
    }
    __builtin_amdgcn_s_setprio(0);

    __builtin_amdgcn_s_barrier();
    asm volatile("" ::: "memory");
    cur ^= 1;
  }

  // final row-sum reduction (once, 16-wide per row-group)
  float lrun[4];
#pragma unroll
  for (int r = 0; r < 4; r++) {
    float t = lsum[r];
#pragma unroll
    for (int off = 8; off >= 1; off >>= 1) t += __shfl_xor(t, off, 16);
    lrun[r] = t;
  }

#pragma unroll
  for (int n = 0; n < 4; n++)
#pragma unroll
    for (int r = 0; r < 4; r++) {
      float v = po[n][r] / lrun[r];
      AO[(size_t)(b*S_ + q0 + w*16 + g*4 + r)*D_ + h*64 + n*16 + r16] = (bf16)v;
    }
}

// ---------------- fused residual + LayerNorm ----------------
template<bool WB>
__global__ __launch_bounds__(256) void ln_res(
    const float* __restrict__ x, const float* __restrict__ r,
    const float* __restrict__ sc, const float* __restrict__ bi,
    float* __restrict__ y, bf16* __restrict__ yb) {
  const int row = blockIdx.x, tid = threadIdx.x;
  const size_t base = (size_t)row * D_;
  float4 a  = ((const float4*)(x + base))[tid];
  float4 b4 = ((const float4*)(r + base))[tid];
  float v[4] = {a.x + b4.x, a.y + b4.y, a.z + b4.z, a.w + b4.w};
  float s  = v[0] + v[1] + v[2] + v[3];
  float ss = v[0]*v[0] + v[1]*v[1] + v[2]*v[2] + v[3]*v[3];
#pragma unroll
  for (int off = 32; off >= 1; off >>= 1) {
    s  += __shfl_xor(s, off, 64);
    ss += __shfl_xor(ss, off, 64);
  }
  __shared__ float red[8];
  const int wv = tid >> 6;
  if ((tid & 63) == 0) { red[wv] = s; red[4 + wv] = ss; }
  __syncthreads();
  s  = red[0] + red[1] + red[2] + red[3];
  ss = red[4] + red[5] + red[6] + red[7];
  const float mu  = s * (1.0f / D_);
  const float inv = rsqrtf(ss * (1.0f / D_) - mu*mu + 1e-6f);
  float4 scv = ((const float4*)sc)[tid];
  float4 biv = ((const float4*)bi)[tid];
  float o[4];
  o[0] = (v[0]-mu)*inv*scv.x + biv.x;
  o[1] = (v[1]-mu)*inv*scv.y + biv.y;
  o[2] = (v[2]-mu)*inv*scv.z + biv.z;
  o[3] = (v[3]-mu)*inv*scv.w + biv.w;
  ((float4*)(y + base))[tid] = make_float4(o[0], o[1], o[2], o[3]);
  if (WB) {
#pragma unroll
    for (int j = 0; j < 4; j++) yb[base + tid*4 + j] = (bf16)o[j];
  }
}

// ---------------- launch ----------------
extern "C" void kernel_launch(void* const* d_in, const int* in_sizes, int n_in,
                              void* d_out, int out_size, void* d_ws, size_t ws_size,
                              hipStream_t stream) {
  const float* X    = (const float*)d_in[0];
  const int*   mask = (const int*)d_in[1];
  const float* Wq   = (const float*)d_in[2];
  const float* bq   = (const float*)d_in[3];
  const float* Wk   = (const float*)d_in[4];
  const float* bk   = (const float*)d_in[5];
  const float* Wv   = (const float*)d_in[6];
  const float* bv   = (const float*)d_in[7];
  const float* Wo   = (const float*)d_in[8];
  const float* bo   = (const float*)d_in[9];
  const float* ln0s = (const float*)d_in[10];
  const float* ln0b = (const float*)d_in[11];
  const float* W1   = (const float*)d_in[12];
  const float* b1   = (const float*)d_in[13];
  const float* W2   = (const float*)d_in[14];
  const float* b2   = (const float*)d_in[15];
  const float* ln1s = (const float*)d_in[16];
  const float* ln1b = (const float*)d_in[17];
  float* out = (float*)d_out;

  char* ws = (char*)d_ws;
  const size_t MB = 1024 * 1024;
  bf16*  Xb    = (bf16*)(ws + 0);        // 8MB
  bf16*  AO    = (bf16*)(ws + 0);        // reuse (Xb dead after QKV gemm)
  bf16*  Wqkvt = (bf16*)(ws + 8*MB);     // 6MB  [3072][1024]
  bf16*  Wot   = (bf16*)(ws + 14*MB);    // 2MB  [1024][1024]
  bf16*  W1t   = (bf16*)(ws + 16*MB);    // 8MB  [4096][1024]
  bf16*  W2t   = (bf16*)(ws + 24*MB);    // 8MB  [1024][4096]
  bf16*  QKV   = (bf16*)(ws + 32*MB);    // 24MB [4096][3072]
  bf16*  Vt    = (bf16*)(ws + 56*MB);    // 8MB  [32][64][2048]
  bf16*  FF1   = (bf16*)(ws + 32*MB);    // 32MB reuse [4096][4096]
  float* Proj  = (float*)(ws + 64*MB);   // 16MB (also FF2 out)
  float* bqkv  = (float*)(ws + 64*MB);   // 12KB, head of Proj (dead by Wo-gemm)
  float* X1    = (float*)(ws + 80*MB);   // 16MB
  bf16*  X1b   = (bf16*)(ws + 96*MB);    // 8MB

  cast_f32_bf16<<<(M_*D_)/1024, 256, 0, stream>>>(X, Xb, M_*D_);
  copy3<<<12, 256, 0, stream>>>(bq, bk, bv, bqkv);
  transpose_cast<<<dim3(D_/32, D_/32), 256, 0, stream>>>(Wq, Wqkvt, D_, D_);
  transpose_cast<<<dim3(D_/32, D_/32), 256, 0, stream>>>(Wk, Wqkvt + (size_t)1024*1024, D_, D_);
  transpose_cast<<<dim3(D_/32, D_/32), 256, 0, stream>>>(Wv, Wqkvt + (size_t)2048*1024, D_, D_);
  transpose_cast<<<dim3(D_/32, D_/32), 256, 0, stream>>>(Wo, Wot, D_, D_);
  transpose_cast<<<dim3(FF_/32, D_/32), 256, 0, stream>>>(W1, W1t, D_, FF_);
  transpose_cast<<<dim3(D_/32, FF_/32), 256, 0, stream>>>(W2, W2t, FF_, D_);

  gemm_bt<false,false><<<dim3(3072/128, M_/128), 256, 0, stream>>>(Xb, Wqkvt, bqkv, QKV, M_, 3072, D_);
  transpose_v<<<dim3(32, S_/64), 256, 0, stream>>>(QKV, Vt);
  attn<<<dim3(32, S_/64), 256, 0, stream>>>(QKV, Vt, mask, AO);
  gemm_bt<true,false><<<dim3(D_/128, M_/128), 256, 0, stream>>>(AO, Wot, bo, Proj, M_, D_, D_);
  ln_res<true><<<M_, 256, 0, stream>>>(X, Proj, ln0s, ln0b, X1, X1b);
  gemm_bt<false,true><<<dim3(FF_/128, M_/128), 256, 0, stream>>>(X1b, W1t, b1, FF1, M_, FF_, D_);
  gemm_bt<true,false><<<dim3(D_/128, M_/128), 256, 0, stream>>>(FF1, W2t, b2, Proj, M_, D_, FF_);
  ln_res<false><<<M_, 256, 0, stream>>>(X1, Proj, ln1s, ln1b, out, nullptr);
}

// Round 6
// 320.004 us; speedup vs baseline: 1.3114x; 1.0852x over previous
//
#include <hip/hip_runtime.h>
#include <hip/hip_bf16.h>
#include <stdint.h>

// Problem constants
#define B_ 2
#define S_ 2048
#define D_ 1024
#define H_ 16
#define DH_ 64
#define FF_ 4096
#define M_ (B_*S_)   // 4096 tokens

typedef __bf16 bf16;
typedef __bf16 bf16x8 __attribute__((ext_vector_type(8)));
typedef float f32x4 __attribute__((ext_vector_type(4)));

// global -> LDS direct load, 16B per lane. LDS dest = wave-uniform base + lane*16.
__device__ __forceinline__ void gload_lds16(const void* g, void* l) {
  auto gp = reinterpret_cast<const __attribute__((address_space(1))) void*>(
      reinterpret_cast<uintptr_t>(g));
  auto lp = reinterpret_cast<__attribute__((address_space(3))) void*>(
      reinterpret_cast<uintptr_t>(l));
  __builtin_amdgcn_global_load_lds(gp, lp, 16, 0, 0);
}

// ---------------- prep kernels ----------------

__global__ __launch_bounds__(256) void cast_f32_bf16(
    const float* __restrict__ in, bf16* __restrict__ out, int n) {
  int i = (blockIdx.x * 256 + threadIdx.x) * 4;
  if (i < n) {
    float4 v = *(const float4*)(in + i);
    out[i+0] = (bf16)v.x; out[i+1] = (bf16)v.y;
    out[i+2] = (bf16)v.z; out[i+3] = (bf16)v.w;
  }
}

__global__ __launch_bounds__(256) void copy3(
    const float* __restrict__ a, const float* __restrict__ b,
    const float* __restrict__ c, float* __restrict__ out) {
  int i = blockIdx.x * 256 + threadIdx.x;   // 0..3071
  out[i] = i < 1024 ? a[i] : (i < 2048 ? b[i-1024] : c[i-2048]);
}

// in [K][N] f32 -> out [N][K] bf16
__global__ __launch_bounds__(256) void transpose_cast(
    const float* __restrict__ in, bf16* __restrict__ out, int K, int N) {
  __shared__ float t[32][33];
  int tx = threadIdx.x & 31, ty = threadIdx.x >> 5;  // ty 0..7
  int n0 = blockIdx.x * 32, k0 = blockIdx.y * 32;
#pragma unroll
  for (int i = 0; i < 4; i++)
    t[ty + i*8][tx] = in[(size_t)(k0 + ty + i*8) * N + n0 + tx];
  __syncthreads();
#pragma unroll
  for (int i = 0; i < 4; i++)
    out[(size_t)(n0 + ty + i*8) * K + k0 + tx] = (bf16)t[tx][ty + i*8];
}

// QKV [4096][3072] (V section) -> Vt [B*H][64][2048]
__global__ __launch_bounds__(256) void transpose_v(
    const bf16* __restrict__ QKV, bf16* __restrict__ Vt) {
  __shared__ bf16 t[64][66];
  int bh = blockIdx.x, s0 = blockIdx.y * 64;
  int b = bh >> 4, h = bh & 15;
  int w = threadIdx.x >> 6, l = threadIdx.x & 63;
#pragma unroll
  for (int i = 0; i < 16; i++) {
    int sr = w*16 + i;
    t[sr][l] = QKV[(size_t)(b*S_ + s0 + sr) * 3072 + 2*D_ + h*DH_ + l];
  }
  __syncthreads();
#pragma unroll
  for (int i = 0; i < 16; i++) {
    int dh = w*16 + i;
    Vt[((size_t)(bh*DH_ + dh)) * S_ + s0 + l] = t[l][dh];
  }
}

// ---------------- GEMM 128x128 (m97 structure) for small-N shapes ----------
template<bool OUTF32, bool RELU>
__global__ __launch_bounds__(256) void gemm_bt(
    const bf16* __restrict__ A, const bf16* __restrict__ Bt,
    const float* __restrict__ bias, void* __restrict__ Cp,
    int M, int N, int K) {
  __shared__ bf16 As[128*32];
  __shared__ bf16 Bs[128*32];
  const int tid = threadIdx.x;
  const int w = tid >> 6, l = tid & 63;
  const int wm = w >> 1, wn = w & 1;
  const int r16 = l & 15, g = l >> 4;

  const int gx = gridDim.x;
  const int nwg = gx * gridDim.y;
  const int lid = blockIdx.y * gx + blockIdx.x;
  const int swz = (lid & 7) * (nwg >> 3) + (lid >> 3);
  const int m0 = (swz / gx) * 128, n0 = (swz % gx) * 128;

  const int srow = w*16 + (l >> 2);
  const int acol8 = (l & 3) * 8;
  const bf16* ag = A + (size_t)(m0 + srow) * K + acol8;
  const bf16* bg = Bt + (size_t)(n0 + srow) * K + acol8;
  bf16* as_base = &As[(w*16) * 32];
  bf16* bs_base = &Bs[(w*16) * 32];

  f32x4 acc[4][4];
#pragma unroll
  for (int i = 0; i < 4; i++)
#pragma unroll
    for (int j = 0; j < 4; j++) acc[i][j] = (f32x4){0.f,0.f,0.f,0.f};

  for (int k0 = 0; k0 < K; k0 += 32) {
#pragma unroll
    for (int p = 0; p < 2; p++) {
      gload_lds16(ag + (size_t)(p*64) * K + k0, as_base + p*64*32);
      gload_lds16(bg + (size_t)(p*64) * K + k0, bs_base + p*64*32);
    }
    __syncthreads();
    bf16x8 af[4], bfr[4];
#pragma unroll
    for (int mi = 0; mi < 4; mi++)
      af[mi] = *(const bf16x8*)&As[(wm*64 + mi*16 + r16) * 32 + g*8];
#pragma unroll
    for (int ni = 0; ni < 4; ni++)
      bfr[ni] = *(const bf16x8*)&Bs[(wn*64 + ni*16 + r16) * 32 + g*8];
#pragma unroll
    for (int mi = 0; mi < 4; mi++)
#pragma unroll
      for (int ni = 0; ni < 4; ni++)
        acc[mi][ni] = __builtin_amdgcn_mfma_f32_16x16x32_bf16(
            af[mi], bfr[ni], acc[mi][ni], 0, 0, 0);
    __syncthreads();
  }

  float bvs[4];
#pragma unroll
  for (int ni = 0; ni < 4; ni++) bvs[ni] = bias[n0 + wn*64 + ni*16 + r16];
#pragma unroll
  for (int mi = 0; mi < 4; mi++)
#pragma unroll
    for (int ni = 0; ni < 4; ni++)
#pragma unroll
      for (int r = 0; r < 4; r++) {
        float v = acc[mi][ni][r] + bvs[ni];
        if (RELU) v = fmaxf(v, 0.f);
        size_t row = (size_t)(m0 + wm*64 + mi*16 + g*4 + r);
        size_t col = (size_t)(n0 + wn*64 + ni*16 + r16);
        if (OUTF32) ((float*)Cp)[row * N + col] = v;
        else        ((bf16*)Cp)[row * N + col] = (bf16)v;
      }
}

// ---------------- GEMM 256x256, BK=64, 8 waves, phased schedule ------------
// LDS tiles [256][64] bf16, XOR-swizzled (chunk ^= row&7) via pre-swizzled
// global source + linear gload_lds dest (attn-verified pattern). Per K-tile:
// issue 8 next-tile gloads early, 4 MFMA phases (16 each), one vmcnt(0)+
// s_barrier per tile. bf16 output only.
template<bool RELU>
__global__ __launch_bounds__(512) void gemm256(
    const bf16* __restrict__ A, const bf16* __restrict__ Bt,
    const float* __restrict__ bias, bf16* __restrict__ C,
    int M, int N, int K) {
  __shared__ bf16 As[2][256*64];   // 64KB
  __shared__ bf16 Bs[2][256*64];   // 64KB
  const int tid = threadIdx.x;
  const int w = tid >> 6, l = tid & 63;
  const int wm = w >> 2, wn = w & 3;     // 2 x 4 wave grid, wave tile 128x64
  const int r16 = l & 15, g = l >> 4;

  const int gx = gridDim.x;
  const int nwg = gx * gridDim.y;
  const int lid = blockIdx.y * gx + blockIdx.x;
  const int swz = (lid & 7) * (nwg >> 3) + (lid >> 3);
  const int m0 = (swz / gx) * 256, n0 = (swz % gx) * 256;

  // staging: round q covers rows q*64 + w*8 + (l>>3), LDS chunk l&7 holds
  // global chunk (l&7)^(row&7); row&7 == l>>3 here.
  const int srow = w*8 + (l >> 3);
  const int sch  = ((l & 7) ^ (l >> 3)) * 8;
  const bf16* ag = A  + (size_t)(m0 + srow) * K + sch;
  const bf16* bg = Bt + (size_t)(n0 + srow) * K + sch;

  f32x4 acc[8][4];
#pragma unroll
  for (int i = 0; i < 8; i++)
#pragma unroll
    for (int j = 0; j < 4; j++) acc[i][j] = (f32x4){0.f,0.f,0.f,0.f};

  // prologue: stage K-tile 0 into buf 0
#pragma unroll
  for (int q = 0; q < 4; q++) {
    gload_lds16(ag + (size_t)(q*64) * K, &As[0][(q*64 + w*8) * 64]);
    gload_lds16(bg + (size_t)(q*64) * K, &Bs[0][(q*64 + w*8) * 64]);
  }
  asm volatile("s_waitcnt vmcnt(0)" ::: "memory");
  __builtin_amdgcn_s_barrier();
  asm volatile("" ::: "memory");

  const int nt = K >> 6;
  int cur = 0;
  for (int t = 0; t < nt; ++t) {
    // issue next K-tile's 8 gloads early (into buf cur^1)
    if (t + 1 < nt) {
      const size_t k0 = (size_t)(t + 1) << 6;
#pragma unroll
      for (int q = 0; q < 4; q++) {
        gload_lds16(ag + (size_t)(q*64) * K + k0, &As[cur^1][(q*64 + w*8) * 64]);
        gload_lds16(bg + (size_t)(q*64) * K + k0, &Bs[cur^1][(q*64 + w*8) * 64]);
      }
    }

    bf16x8 af[4][2], blo[2][2], bhi[2][2];
    // fragments: row-swizzled reads (chunk (kk*4+g) ^ (row&7))
#pragma unroll
    for (int mi = 0; mi < 4; mi++)
#pragma unroll
      for (int kk = 0; kk < 2; kk++) {
        const int row = wm*128 + mi*16 + r16;
        af[mi][kk] = *(const bf16x8*)&As[cur][row*64 + (((kk*4+g) ^ (row & 7)))*8];
      }
#pragma unroll
    for (int ni = 0; ni < 2; ni++)
#pragma unroll
      for (int kk = 0; kk < 2; kk++) {
        const int row = wn*64 + ni*16 + r16;
        blo[ni][kk] = *(const bf16x8*)&Bs[cur][row*64 + (((kk*4+g) ^ (row & 7)))*8];
      }
    // phase 0: quadrant (miH0, niH0)
    __builtin_amdgcn_s_setprio(1);
#pragma unroll
    for (int mi = 0; mi < 4; mi++)
#pragma unroll
      for (int ni = 0; ni < 2; ni++)
#pragma unroll
        for (int kk = 0; kk < 2; kk++)
          acc[mi][ni] = __builtin_amdgcn_mfma_f32_16x16x32_bf16(
              af[mi][kk], blo[ni][kk], acc[mi][ni], 0, 0, 0);
    __builtin_amdgcn_s_setprio(0);
    // phase 1: (miH0, niH1)
#pragma unroll
    for (int ni = 0; ni < 2; ni++)
#pragma unroll
      for (int kk = 0; kk < 2; kk++) {
        const int row = wn*64 + 32 + ni*16 + r16;
        bhi[ni][kk] = *(const bf16x8*)&Bs[cur][row*64 + (((kk*4+g) ^ (row & 7)))*8];
      }
    __builtin_amdgcn_s_setprio(1);
#pragma unroll
    for (int mi = 0; mi < 4; mi++)
#pragma unroll
      for (int ni = 0; ni < 2; ni++)
#pragma unroll
        for (int kk = 0; kk < 2; kk++)
          acc[mi][2+ni] = __builtin_amdgcn_mfma_f32_16x16x32_bf16(
              af[mi][kk], bhi[ni][kk], acc[mi][2+ni], 0, 0, 0);
    __builtin_amdgcn_s_setprio(0);
    // phase 2: (miH1, niH1) — reload af with high rows
#pragma unroll
    for (int mi = 0; mi < 4; mi++)
#pragma unroll
      for (int kk = 0; kk < 2; kk++) {
        const int row = wm*128 + 64 + mi*16 + r16;
        af[mi][kk] = *(const bf16x8*)&As[cur][row*64 + (((kk*4+g) ^ (row & 7)))*8];
      }
    __builtin_amdgcn_s_setprio(1);
#pragma unroll
    for (int mi = 0; mi < 4; mi++)
#pragma unroll
      for (int ni = 0; ni < 2; ni++)
#pragma unroll
        for (int kk = 0; kk < 2; kk++)
          acc[4+mi][2+ni] = __builtin_amdgcn_mfma_f32_16x16x32_bf16(
              af[mi][kk], bhi[ni][kk], acc[4+mi][2+ni], 0, 0, 0);
    __builtin_amdgcn_s_setprio(0);
    // phase 3: (miH1, niH0) — no new reads
    __builtin_amdgcn_s_setprio(1);
#pragma unroll
    for (int mi = 0; mi < 4; mi++)
#pragma unroll
      for (int ni = 0; ni < 2; ni++)
#pragma unroll
        for (int kk = 0; kk < 2; kk++)
          acc[4+mi][ni] = __builtin_amdgcn_mfma_f32_16x16x32_bf16(
              af[mi][kk], blo[ni][kk], acc[4+mi][ni], 0, 0, 0);
    __builtin_amdgcn_s_setprio(0);

    asm volatile("s_waitcnt vmcnt(0)" ::: "memory");
    __builtin_amdgcn_s_barrier();
    asm volatile("" ::: "memory");
    cur ^= 1;
  }

  float bvs[4];
#pragma unroll
  for (int ni = 0; ni < 4; ni++) bvs[ni] = bias[n0 + wn*64 + ni*16 + r16];
#pragma unroll
  for (int mi = 0; mi < 8; mi++)
#pragma unroll
    for (int ni = 0; ni < 4; ni++)
#pragma unroll
      for (int r = 0; r < 4; r++) {
        float v = acc[mi][ni][r] + bvs[ni];
        if (RELU) v = fmaxf(v, 0.f);
        C[(size_t)(m0 + wm*128 + mi*16 + g*4 + r) * N +
          (n0 + wn*64 + ni*16 + r16)] = (bf16)v;
      }
}

// ---------------- flash attention ----------------
// grid (B*H, S/64); 4 waves, wave w owns 16 q rows. KVBLK=64, double-buffered
// K/V staging with counted vmcnt + raw barriers. Lane-local deferred softmax.
__global__ __launch_bounds__(256) void attn(
    const bf16* __restrict__ QKV, const bf16* __restrict__ Vt,
    const int* __restrict__ mask, bf16* __restrict__ AO) {
  __shared__ bf16 Ks[2][64*64];   // [kv][dh], chunk ^= (kv&7), 16KB
  __shared__ bf16 Vs[2][64*64];   // [dh][kv], chunk ^= (dh&7), 16KB
  __shared__ bf16 Ps[4][16*72];   // per-wave P, row stride 72 elems (144B)
  __shared__ float Mk[S_];

  const int bh = blockIdx.x, b = bh >> 4, h = bh & 15;
  const int q0 = blockIdx.y * 64;
  const int tid = threadIdx.x, w = tid >> 6, l = tid & 63;
  const int r16 = l & 15, g = l >> 4;

  bf16x8 qf[2];
  const size_t qrow = (size_t)(b*S_ + q0 + w*16 + r16);
#pragma unroll
  for (int kk = 0; kk < 2; kk++)
    qf[kk] = *(const bf16x8*)&QKV[qrow*3072 + h*64 + kk*32 + g*8];

  for (int i = tid; i < S_; i += 256) Mk[i] = -10000.0f * (float)mask[b*S_ + i];
  asm volatile("s_waitcnt lgkmcnt(0)" ::: "memory");

  const int srow = w*8 + (l >> 3);
  const int sch  = (l & 7) ^ (l >> 3);
  const bf16* kg = QKV + ((size_t)(b*S_) + srow)*3072 + 1024 + h*64 + sch*8;
  const bf16* vg = Vt + ((size_t)(bh*64 + srow))*S_ + sch*8;

  f32x4 po[4];
#pragma unroll
  for (int n = 0; n < 4; n++) po[n] = (f32x4){0.f,0.f,0.f,0.f};
  float mrun[4], lsum[4];
#pragma unroll
  for (int r = 0; r < 4; r++) { mrun[r] = -1.0e30f; lsum[r] = 0.f; }

#pragma unroll
  for (int p = 0; p < 2; p++) {
    gload_lds16(kg + (size_t)(p*32)*3072, &Ks[0][(p*256 + w*64)*8]);
    gload_lds16(vg + (size_t)(p*32)*S_,   &Vs[0][(p*256 + w*64)*8]);
  }

  int cur = 0;
  for (int it = 0; it < S_/64; ++it) {
    const int kv0 = it * 64;
    if (it + 1 < S_/64) {
#pragma unroll
      for (int p = 0; p < 2; p++) {
        gload_lds16(kg + (size_t)(kv0 + 64 + p*32)*3072, &Ks[cur^1][(p*256 + w*64)*8]);
        gload_lds16(vg + (size_t)(p*32)*S_ + (kv0 + 64), &Vs[cur^1][(p*256 + w*64)*8]);
      }
      asm volatile("s_waitcnt vmcnt(4)" ::: "memory");
    } else {
      asm volatile("s_waitcnt vmcnt(0)" ::: "memory");
    }
    __builtin_amdgcn_s_barrier();
    asm volatile("" ::: "memory");

    float sv[4][4];
    __builtin_amdgcn_s_setprio(1);
#pragma unroll
    for (int ct = 0; ct < 4; ct++) {
      f32x4 s = (f32x4){0.f,0.f,0.f,0.f};
#pragma unroll
      for (int kk = 0; kk < 2; kk++) {
        const int row = ct*16 + r16;
        bf16x8 kf = *(const bf16x8*)&Ks[cur][row*64 + ((kk*4 + g) ^ (row & 7))*8];
        s = __builtin_amdgcn_mfma_f32_16x16x32_bf16(qf[kk], kf, s, 0, 0, 0);
      }
      float madd = Mk[kv0 + ct*16 + r16];
#pragma unroll
      for (int r = 0; r < 4; r++) sv[ct][r] = s[r]*0.125f + madd;
    }
    __builtin_amdgcn_s_setprio(0);

    float lmax[4];
#pragma unroll
    for (int r = 0; r < 4; r++)
      lmax[r] = fmaxf(fmaxf(sv[0][r], sv[1][r]), fmaxf(sv[2][r], sv[3][r]));
    bool grow = (lmax[0] > mrun[0] + 8.f) | (lmax[1] > mrun[1] + 8.f) |
                (lmax[2] > mrun[2] + 8.f) | (lmax[3] > mrun[3] + 8.f);
    if (__any(grow)) {
#pragma unroll
      for (int r = 0; r < 4; r++) {
        float t = lmax[r];
#pragma unroll
        for (int off = 8; off >= 1; off >>= 1) t = fmaxf(t, __shfl_xor(t, off, 16));
        float mnew = fmaxf(mrun[r], t);
        float sc = __expf(mrun[r] - mnew);
        mrun[r] = mnew;
        lsum[r] *= sc;
#pragma unroll
        for (int n = 0; n < 4; n++) po[n][r] *= sc;
      }
    }
    float pr[4][4];
#pragma unroll
    for (int r = 0; r < 4; r++) {
#pragma unroll
      for (int ct = 0; ct < 4; ct++)
        pr[ct][r] = __expf(sv[ct][r] - mrun[r]);
      lsum[r] += (pr[0][r] + pr[1][r]) + (pr[2][r] + pr[3][r]);
    }

#pragma unroll
    for (int ct = 0; ct < 4; ct++)
#pragma unroll
      for (int r = 0; r < 4; r++)
        Ps[w][(g*4 + r)*72 + ct*16 + r16] = (bf16)pr[ct][r];
    asm volatile("s_waitcnt lgkmcnt(0)" ::: "memory");

    __builtin_amdgcn_s_setprio(1);
#pragma unroll
    for (int kk = 0; kk < 2; kk++) {
      bf16x8 pa = *(const bf16x8*)&Ps[w][r16*72 + kk*32 + g*8];
#pragma unroll
      for (int n = 0; n < 4; n++) {
        const int row = n*16 + r16;
        bf16x8 vf = *(const bf16x8*)&Vs[cur][row*64 + ((kk*4 + g) ^ (row & 7))*8];
        po[n] = __builtin_amdgcn_mfma_f32_16x16x32_bf16(pa, vf, po[n], 0, 0, 0);
      }
    }
    __builtin_amdgcn_s_setprio(0);

    __builtin_amdgcn_s_barrier();
    asm volatile("" ::: "memory");
    cur ^= 1;
  }

  float lrun[4];
#pragma unroll
  for (int r = 0; r < 4; r++) {
    float t = lsum[r];
#pragma unroll
    for (int off = 8; off >= 1; off >>= 1) t += __shfl_xor(t, off, 16);
    lrun[r] = t;
  }

#pragma unroll
  for (int n = 0; n < 4; n++)
#pragma unroll
    for (int r = 0; r < 4; r++) {
      float v = po[n][r] / lrun[r];
      AO[(size_t)(b*S_ + q0 + w*16 + g*4 + r)*D_ + h*64 + n*16 + r16] = (bf16)v;
    }
}

// ---------------- fused residual + LayerNorm ----------------
template<bool WB>
__global__ __launch_bounds__(256) void ln_res(
    const float* __restrict__ x, const float* __restrict__ r,
    const float* __restrict__ sc, const float* __restrict__ bi,
    float* __restrict__ y, bf16* __restrict__ yb) {
  const int row = blockIdx.x, tid = threadIdx.x;
  const size_t base = (size_t)row * D_;
  float4 a  = ((const float4*)(x + base))[tid];
  float4 b4 = ((const float4*)(r + base))[tid];
  float v[4] = {a.x + b4.x, a.y + b4.y, a.z + b4.z, a.w + b4.w};
  float s  = v[0] + v[1] + v[2] + v[3];
  float ss = v[0]*v[0] + v[1]*v[1] + v[2]*v[2] + v[3]*v[3];
#pragma unroll
  for (int off = 32; off >= 1; off >>= 1) {
    s  += __shfl_xor(s, off, 64);
    ss += __shfl_xor(ss, off, 64);
  }
  __shared__ float red[8];
  const int wv = tid >> 6;
  if ((tid & 63) == 0) { red[wv] = s; red[4 + wv] = ss; }
  __syncthreads();
  s  = red[0] + red[1] + red[2] + red[3];
  ss = red[4] + red[5] + red[6] + red[7];
  const float mu  = s * (1.0f / D_);
  const float inv = rsqrtf(ss * (1.0f / D_) - mu*mu + 1e-6f);
  float4 scv = ((const float4*)sc)[tid];
  float4 biv = ((const float4*)bi)[tid];
  float o[4];
  o[0] = (v[0]-mu)*inv*scv.x + biv.x;
  o[1] = (v[1]-mu)*inv*scv.y + biv.y;
  o[2] = (v[2]-mu)*inv*scv.z + biv.z;
  o[3] = (v[3]-mu)*inv*scv.w + biv.w;
  ((float4*)(y + base))[tid] = make_float4(o[0], o[1], o[2], o[3]);
  if (WB) {
#pragma unroll
    for (int j = 0; j < 4; j++) yb[base + tid*4 + j] = (bf16)o[j];
  }
}

// ---------------- launch ----------------
extern "C" void kernel_launch(void* const* d_in, const int* in_sizes, int n_in,
                              void* d_out, int out_size, void* d_ws, size_t ws_size,
                              hipStream_t stream) {
  const float* X    = (const float*)d_in[0];
  const int*   mask = (const int*)d_in[1];
  const float* Wq   = (const float*)d_in[2];
  const float* bq   = (const float*)d_in[3];
  const float* Wk   = (const float*)d_in[4];
  const float* bk   = (const float*)d_in[5];
  const float* Wv   = (const float*)d_in[6];
  const float* bv   = (const float*)d_in[7];
  const float* Wo   = (const float*)d_in[8];
  const float* bo   = (const float*)d_in[9];
  const float* ln0s = (const float*)d_in[10];
  const float* ln0b = (const float*)d_in[11];
  const float* W1   = (const float*)d_in[12];
  const float* b1   = (const float*)d_in[13];
  const float* W2   = (const float*)d_in[14];
  const float* b2   = (const float*)d_in[15];
  const float* ln1s = (const float*)d_in[16];
  const float* ln1b = (const float*)d_in[17];
  float* out = (float*)d_out;

  char* ws = (char*)d_ws;
  const size_t MB = 1024 * 1024;
  bf16*  Xb    = (bf16*)(ws + 0);        // 8MB
  bf16*  AO    = (bf16*)(ws + 0);        // reuse (Xb dead after QKV gemm)
  bf16*  Wqkvt = (bf16*)(ws + 8*MB);     // 6MB  [3072][1024]
  bf16*  Wot   = (bf16*)(ws + 14*MB);    // 2MB  [1024][1024]
  bf16*  W1t   = (bf16*)(ws + 16*MB);    // 8MB  [4096][1024]
  bf16*  W2t   = (bf16*)(ws + 24*MB);    // 8MB  [1024][4096]
  bf16*  QKV   = (bf16*)(ws + 32*MB);    // 24MB [4096][3072]
  bf16*  Vt    = (bf16*)(ws + 56*MB);    // 8MB  [32][64][2048]
  bf16*  FF1   = (bf16*)(ws + 32*MB);    // 32MB reuse [4096][4096]
  float* Proj  = (float*)(ws + 64*MB);   // 16MB (also FF2 out)
  float* bqkv  = (float*)(ws + 64*MB);   // 12KB, head of Proj (dead by Wo-gemm)
  float* X1    = (float*)(ws + 80*MB);   // 16MB
  bf16*  X1b   = (bf16*)(ws + 96*MB);    // 8MB

  cast_f32_bf16<<<(M_*D_)/1024, 256, 0, stream>>>(X, Xb, M_*D_);
  copy3<<<12, 256, 0, stream>>>(bq, bk, bv, bqkv);
  transpose_cast<<<dim3(D_/32, D_/32), 256, 0, stream>>>(Wq, Wqkvt, D_, D_);
  transpose_cast<<<dim3(D_/32, D_/32), 256, 0, stream>>>(Wk, Wqkvt + (size_t)1024*1024, D_, D_);
  transpose_cast<<<dim3(D_/32, D_/32), 256, 0, stream>>>(Wv, Wqkvt + (size_t)2048*1024, D_, D_);
  transpose_cast<<<dim3(D_/32, D_/32), 256, 0, stream>>>(Wo, Wot, D_, D_);
  transpose_cast<<<dim3(FF_/32, D_/32), 256, 0, stream>>>(W1, W1t, D_, FF_);
  transpose_cast<<<dim3(D_/32, FF_/32), 256, 0, stream>>>(W2, W2t, FF_, D_);

  gemm256<false><<<dim3(3072/256, M_/256), 512, 0, stream>>>(Xb, Wqkvt, bqkv, QKV, M_, 3072, D_);
  transpose_v<<<dim3(32, S_/64), 256, 0, stream>>>(QKV, Vt);
  attn<<<dim3(32, S_/64), 256, 0, stream>>>(QKV, Vt, mask, AO);
  gemm_bt<true,false><<<dim3(D_/128, M_/128), 256, 0, stream>>>(AO, Wot, bo, Proj, M_, D_, D_);
  ln_res<true><<<M_, 256, 0, stream>>>(X, Proj, ln0s, ln0b, X1, X1b);
  gemm256<true><<<dim3(FF_/256, M_/256), 512, 0, stream>>>(X1b, W1t, b1, FF1, M_, FF_, D_);
  gemm_bt<true,false><<<dim3(D_/128, M_/128), 256, 0, stream>>>(FF1, W2t, b2, Proj, M_, D_, FF_);
  ln_res<false><<<M_, 256, 0, stream>>>(X1, Proj, ln1s, ln1b, out, nullptr);
}

// Round 7
// 304.298 us; speedup vs baseline: 1.3790x; 1.0516x over previous
//
#include <hip/hip_runtime.h>
#include <hip/hip_bf16.h>
#include <stdint.h>

// Problem constants
#define B_ 2
#define S_ 2048
#define D_ 1024
#define H_ 16
#define DH_ 64
#define FF_ 4096
#define M_ (B_*S_)   // 4096 tokens

typedef __bf16 bf16;
typedef __bf16 bf16x4 __attribute__((ext_vector_type(4)));
typedef __bf16 bf16x8 __attribute__((ext_vector_type(8)));
typedef float f32x4 __attribute__((ext_vector_type(4)));

// global -> LDS direct load, 16B per lane. LDS dest = wave-uniform base + lane*16.
__device__ __forceinline__ void gload_lds16(const void* g, void* l) {
  auto gp = reinterpret_cast<const __attribute__((address_space(1))) void*>(
      reinterpret_cast<uintptr_t>(g));
  auto lp = reinterpret_cast<__attribute__((address_space(3))) void*>(
      reinterpret_cast<uintptr_t>(l));
  __builtin_amdgcn_global_load_lds(gp, lp, 16, 0, 0);
}

// ---------------- prep kernels ----------------

__global__ __launch_bounds__(256) void cast_f32_bf16(
    const float* __restrict__ in, bf16* __restrict__ out, int n) {
  int i = (blockIdx.x * 256 + threadIdx.x) * 4;
  if (i < n) {
    float4 v = *(const float4*)(in + i);
    out[i+0] = (bf16)v.x; out[i+1] = (bf16)v.y;
    out[i+2] = (bf16)v.z; out[i+3] = (bf16)v.w;
  }
}

__global__ __launch_bounds__(256) void copy3(
    const float* __restrict__ a, const float* __restrict__ b,
    const float* __restrict__ c, float* __restrict__ out) {
  int i = blockIdx.x * 256 + threadIdx.x;   // 0..3071
  out[i] = i < 1024 ? a[i] : (i < 2048 ? b[i-1024] : c[i-2048]);
}

__global__ __launch_bounds__(256) void prep_mask(
    const int* __restrict__ mask, float* __restrict__ Mp) {
  int i = blockIdx.x * 256 + threadIdx.x;   // 0..4095
  Mp[i] = -10000.0f * (float)mask[i];
}

// in [K][N] f32 -> out [N][K] bf16
__global__ __launch_bounds__(256) void transpose_cast(
    const float* __restrict__ in, bf16* __restrict__ out, int K, int N) {
  __shared__ float t[32][33];
  int tx = threadIdx.x & 31, ty = threadIdx.x >> 5;  // ty 0..7
  int n0 = blockIdx.x * 32, k0 = blockIdx.y * 32;
#pragma unroll
  for (int i = 0; i < 4; i++)
    t[ty + i*8][tx] = in[(size_t)(k0 + ty + i*8) * N + n0 + tx];
  __syncthreads();
#pragma unroll
  for (int i = 0; i < 4; i++)
    out[(size_t)(n0 + ty + i*8) * K + k0 + tx] = (bf16)t[tx][ty + i*8];
}

// QKV [4096][3072] (V section) -> Vt [B*H][64][2048], kv'-permuted within
// each 64-chunk: column s0 + (l&15)*4 + (l>>4) holds kv = s0 + l. This
// matches the P-store layout in attn (P col = r16*4 + ct), so PV sums over
// the same permuted k ordering (matmul is permutation-invariant over k).
__global__ __launch_bounds__(256) void transpose_v(
    const bf16* __restrict__ QKV, bf16* __restrict__ Vt) {
  __shared__ bf16 t[64][66];
  int bh = blockIdx.x, s0 = blockIdx.y * 64;
  int b = bh >> 4, h = bh & 15;
  int w = threadIdx.x >> 6, l = threadIdx.x & 63;
#pragma unroll
  for (int i = 0; i < 16; i++) {
    int sr = w*16 + i;
    t[sr][l] = QKV[(size_t)(b*S_ + s0 + sr) * 3072 + 2*D_ + h*DH_ + l];
  }
  __syncthreads();
  const int pcol = (l & 15) * 4 + (l >> 4);   // perm(l)
#pragma unroll
  for (int i = 0; i < 16; i++) {
    int dh = w*16 + i;
    Vt[((size_t)(bh*DH_ + dh)) * S_ + s0 + pcol] = t[l][dh];
  }
}

// ---------------- GEMM 128x128 (m97 structure) for small-N shapes ----------
template<bool OUTF32, bool RELU>
__global__ __launch_bounds__(256) void gemm_bt(
    const bf16* __restrict__ A, const bf16* __restrict__ Bt,
    const float* __restrict__ bias, void* __restrict__ Cp,
    int M, int N, int K) {
  __shared__ bf16 As[128*32];
  __shared__ bf16 Bs[128*32];
  const int tid = threadIdx.x;
  const int w = tid >> 6, l = tid & 63;
  const int wm = w >> 1, wn = w & 1;
  const int r16 = l & 15, g = l >> 4;

  const int gx = gridDim.x;
  const int nwg = gx * gridDim.y;
  const int lid = blockIdx.y * gx + blockIdx.x;
  const int swz = (lid & 7) * (nwg >> 3) + (lid >> 3);
  const int m0 = (swz / gx) * 128, n0 = (swz % gx) * 128;

  const int srow = w*16 + (l >> 2);
  const int acol8 = (l & 3) * 8;
  const bf16* ag = A + (size_t)(m0 + srow) * K + acol8;
  const bf16* bg = Bt + (size_t)(n0 + srow) * K + acol8;
  bf16* as_base = &As[(w*16) * 32];
  bf16* bs_base = &Bs[(w*16) * 32];

  f32x4 acc[4][4];
#pragma unroll
  for (int i = 0; i < 4; i++)
#pragma unroll
    for (int j = 0; j < 4; j++) acc[i][j] = (f32x4){0.f,0.f,0.f,0.f};

  for (int k0 = 0; k0 < K; k0 += 32) {
#pragma unroll
    for (int p = 0; p < 2; p++) {
      gload_lds16(ag + (size_t)(p*64) * K + k0, as_base + p*64*32);
      gload_lds16(bg + (size_t)(p*64) * K + k0, bs_base + p*64*32);
    }
    __syncthreads();
    bf16x8 af[4], bfr[4];
#pragma unroll
    for (int mi = 0; mi < 4; mi++)
      af[mi] = *(const bf16x8*)&As[(wm*64 + mi*16 + r16) * 32 + g*8];
#pragma unroll
    for (int ni = 0; ni < 4; ni++)
      bfr[ni] = *(const bf16x8*)&Bs[(wn*64 + ni*16 + r16) * 32 + g*8];
#pragma unroll
    for (int mi = 0; mi < 4; mi++)
#pragma unroll
      for (int ni = 0; ni < 4; ni++)
        acc[mi][ni] = __builtin_amdgcn_mfma_f32_16x16x32_bf16(
            af[mi], bfr[ni], acc[mi][ni], 0, 0, 0);
    __syncthreads();
  }

  float bvs[4];
#pragma unroll
  for (int ni = 0; ni < 4; ni++) bvs[ni] = bias[n0 + wn*64 + ni*16 + r16];
#pragma unroll
  for (int mi = 0; mi < 4; mi++)
#pragma unroll
    for (int ni = 0; ni < 4; ni++)
#pragma unroll
      for (int r = 0; r < 4; r++) {
        float v = acc[mi][ni][r] + bvs[ni];
        if (RELU) v = fmaxf(v, 0.f);
        size_t row = (size_t)(m0 + wm*64 + mi*16 + g*4 + r);
        size_t col = (size_t)(n0 + wn*64 + ni*16 + r16);
        if (OUTF32) ((float*)Cp)[row * N + col] = v;
        else        ((bf16*)Cp)[row * N + col] = (bf16)v;
      }
}

// ---------------- GEMM 256x256, BK=64, 8 waves, phased schedule ------------
template<bool RELU>
__global__ __launch_bounds__(512) void gemm256(
    const bf16* __restrict__ A, const bf16* __restrict__ Bt,
    const float* __restrict__ bias, bf16* __restrict__ C,
    int M, int N, int K) {
  __shared__ bf16 As[2][256*64];   // 64KB
  __shared__ bf16 Bs[2][256*64];   // 64KB
  const int tid = threadIdx.x;
  const int w = tid >> 6, l = tid & 63;
  const int wm = w >> 2, wn = w & 3;     // 2 x 4 wave grid, wave tile 128x64
  const int r16 = l & 15, g = l >> 4;

  const int gx = gridDim.x;
  const int nwg = gx * gridDim.y;
  const int lid = blockIdx.y * gx + blockIdx.x;
  const int swz = (lid & 7) * (nwg >> 3) + (lid >> 3);
  const int m0 = (swz / gx) * 256, n0 = (swz % gx) * 256;

  const int srow = w*8 + (l >> 3);
  const int sch  = ((l & 7) ^ (l >> 3)) * 8;
  const bf16* ag = A  + (size_t)(m0 + srow) * K + sch;
  const bf16* bg = Bt + (size_t)(n0 + srow) * K + sch;

  f32x4 acc[8][4];
#pragma unroll
  for (int i = 0; i < 8; i++)
#pragma unroll
    for (int j = 0; j < 4; j++) acc[i][j] = (f32x4){0.f,0.f,0.f,0.f};

#pragma unroll
  for (int q = 0; q < 4; q++) {
    gload_lds16(ag + (size_t)(q*64) * K, &As[0][(q*64 + w*8) * 64]);
    gload_lds16(bg + (size_t)(q*64) * K, &Bs[0][(q*64 + w*8) * 64]);
  }
  asm volatile("s_waitcnt vmcnt(0)" ::: "memory");
  __builtin_amdgcn_s_barrier();
  asm volatile("" ::: "memory");

  const int nt = K >> 6;
  int cur = 0;
  for (int t = 0; t < nt; ++t) {
    if (t + 1 < nt) {
      const size_t k0 = (size_t)(t + 1) << 6;
#pragma unroll
      for (int q = 0; q < 4; q++) {
        gload_lds16(ag + (size_t)(q*64) * K + k0, &As[cur^1][(q*64 + w*8) * 64]);
        gload_lds16(bg + (size_t)(q*64) * K + k0, &Bs[cur^1][(q*64 + w*8) * 64]);
      }
    }

    bf16x8 af[4][2], blo[2][2], bhi[2][2];
#pragma unroll
    for (int mi = 0; mi < 4; mi++)
#pragma unroll
      for (int kk = 0; kk < 2; kk++) {
        const int row = wm*128 + mi*16 + r16;
        af[mi][kk] = *(const bf16x8*)&As[cur][row*64 + (((kk*4+g) ^ (row & 7)))*8];
      }
#pragma unroll
    for (int ni = 0; ni < 2; ni++)
#pragma unroll
      for (int kk = 0; kk < 2; kk++) {
        const int row = wn*64 + ni*16 + r16;
        blo[ni][kk] = *(const bf16x8*)&Bs[cur][row*64 + (((kk*4+g) ^ (row & 7)))*8];
      }
    __builtin_amdgcn_s_setprio(1);
#pragma unroll
    for (int mi = 0; mi < 4; mi++)
#pragma unroll
      for (int ni = 0; ni < 2; ni++)
#pragma unroll
        for (int kk = 0; kk < 2; kk++)
          acc[mi][ni] = __builtin_amdgcn_mfma_f32_16x16x32_bf16(
              af[mi][kk], blo[ni][kk], acc[mi][ni], 0, 0, 0);
    __builtin_amdgcn_s_setprio(0);
#pragma unroll
    for (int ni = 0; ni < 2; ni++)
#pragma unroll
      for (int kk = 0; kk < 2; kk++) {
        const int row = wn*64 + 32 + ni*16 + r16;
        bhi[ni][kk] = *(const bf16x8*)&Bs[cur][row*64 + (((kk*4+g) ^ (row & 7)))*8];
      }
    __builtin_amdgcn_s_setprio(1);
#pragma unroll
    for (int mi = 0; mi < 4; mi++)
#pragma unroll
      for (int ni = 0; ni < 2; ni++)
#pragma unroll
        for (int kk = 0; kk < 2; kk++)
          acc[mi][2+ni] = __builtin_amdgcn_mfma_f32_16x16x32_bf16(
              af[mi][kk], bhi[ni][kk], acc[mi][2+ni], 0, 0, 0);
    __builtin_amdgcn_s_setprio(0);
#pragma unroll
    for (int mi = 0; mi < 4; mi++)
#pragma unroll
      for (int kk = 0; kk < 2; kk++) {
        const int row = wm*128 + 64 + mi*16 + r16;
        af[mi][kk] = *(const bf16x8*)&As[cur][row*64 + (((kk*4+g) ^ (row & 7)))*8];
      }
    __builtin_amdgcn_s_setprio(1);
#pragma unroll
    for (int mi = 0; mi < 4; mi++)
#pragma unroll
      for (int ni = 0; ni < 2; ni++)
#pragma unroll
        for (int kk = 0; kk < 2; kk++)
          acc[4+mi][2+ni] = __builtin_amdgcn_mfma_f32_16x16x32_bf16(
              af[mi][kk], bhi[ni][kk], acc[4+mi][2+ni], 0, 0, 0);
    __builtin_amdgcn_s_setprio(0);
    __builtin_amdgcn_s_setprio(1);
#pragma unroll
    for (int mi = 0; mi < 4; mi++)
#pragma unroll
      for (int ni = 0; ni < 2; ni++)
#pragma unroll
        for (int kk = 0; kk < 2; kk++)
          acc[4+mi][ni] = __builtin_amdgcn_mfma_f32_16x16x32_bf16(
              af[mi][kk], blo[ni][kk], acc[4+mi][ni], 0, 0, 0);
    __builtin_amdgcn_s_setprio(0);

    asm volatile("s_waitcnt vmcnt(0)" ::: "memory");
    __builtin_amdgcn_s_barrier();
    asm volatile("" ::: "memory");
    cur ^= 1;
  }

  float bvs[4];
#pragma unroll
  for (int ni = 0; ni < 4; ni++) bvs[ni] = bias[n0 + wn*64 + ni*16 + r16];
#pragma unroll
  for (int mi = 0; mi < 8; mi++)
#pragma unroll
    for (int ni = 0; ni < 4; ni++)
#pragma unroll
      for (int r = 0; r < 4; r++) {
        float v = acc[mi][ni][r] + bvs[ni];
        if (RELU) v = fmaxf(v, 0.f);
        C[(size_t)(m0 + wm*128 + mi*16 + g*4 + r) * N +
          (n0 + wn*64 + ni*16 + r16)] = (bf16)v;
      }
}

// ---------------- flash attention ----------------
// grid (B*H, S/128); 4 waves, wave w owns 32 q rows (2 subtiles of 16).
// KVBLK=64, double-buffered K/V staging, counted vmcnt + raw barriers.
// kf/vf fragments read once per iter, used by both q-subtiles (2x reuse).
// P stored kv'-permuted (col = r16*4+ct) -> packed ds_write_b64; V columns
// carry the same permutation (transpose_v).
// Mask additive values prefetched from global (Mp, f32) one iter ahead.
__global__ __launch_bounds__(256) void attn(
    const bf16* __restrict__ QKV, const bf16* __restrict__ Vt,
    const float* __restrict__ Mp, bf16* __restrict__ AO) {
  __shared__ bf16 Ks[2][64*64];   // [kv][dh], chunk ^= (kv&7), 16KB
  __shared__ bf16 Vs[2][64*64];   // [dh][kv'], chunk ^= (dh&7), 16KB
  __shared__ bf16 Ps[4][32*72];   // per-wave P, 32 rows, stride 72 (18KB)

  const int bh = blockIdx.x, b = bh >> 4, h = bh & 15;
  const int q0 = blockIdx.y * 128;
  const int tid = threadIdx.x, w = tid >> 6, l = tid & 63;
  const int r16 = l & 15, g = l >> 4;
  const int qw = q0 + w*32;

  // Q fragments: subtile s (0/1), lane row r16, k = kk*32 + g*8..+7
  bf16x8 qf[2][2];
#pragma unroll
  for (int s = 0; s < 2; s++)
#pragma unroll
    for (int kk = 0; kk < 2; kk++)
      qf[s][kk] = *(const bf16x8*)&QKV[((size_t)(b*S_ + qw + s*16 + r16))*3072
                                       + h*64 + kk*32 + g*8];

  const int srow = w*8 + (l >> 3);
  const int sch  = (l & 7) ^ (l >> 3);
  const bf16* kg = QKV + ((size_t)(b*S_) + srow)*3072 + 1024 + h*64 + sch*8;
  const bf16* vg = Vt + ((size_t)(bh*64 + srow))*S_ + sch*8;

  f32x4 po[2][4];
#pragma unroll
  for (int s = 0; s < 2; s++)
#pragma unroll
    for (int n = 0; n < 4; n++) po[s][n] = (f32x4){0.f,0.f,0.f,0.f};
  float mrun[8], lsum[8];
#pragma unroll
  for (int r = 0; r < 8; r++) { mrun[r] = -1.0e30f; lsum[r] = 0.f; }

  // prologue: madd for tile 0, then stage tile 0 (order matters for vmcnt)
  float madd[4];
#pragma unroll
  for (int ct = 0; ct < 4; ct++) madd[ct] = Mp[b*S_ + ct*16 + r16];
#pragma unroll
  for (int p = 0; p < 2; p++) {
    gload_lds16(kg + (size_t)(p*32)*3072, &Ks[0][(p*256 + w*64)*8]);
    gload_lds16(vg + (size_t)(p*32)*S_,   &Vs[0][(p*256 + w*64)*8]);
  }

  const int NT = S_/64;
  int cur = 0;
  for (int it = 0; it < NT; ++it) {
    const int kv0 = it * 64;
    if (it + 1 < NT) {
#pragma unroll
      for (int p = 0; p < 2; p++) {
        gload_lds16(kg + (size_t)(kv0 + 64 + p*32)*3072, &Ks[cur^1][(p*256 + w*64)*8]);
        gload_lds16(vg + (size_t)(p*32)*S_ + (kv0 + 64), &Vs[cur^1][(p*256 + w*64)*8]);
      }
      // outstanding: [stage_cur(4) old, madd(4), stage_next(4) new] -> keep 4
      asm volatile("s_waitcnt vmcnt(4)" ::: "memory");
    } else {
      asm volatile("s_waitcnt vmcnt(0)" ::: "memory");
    }
    __builtin_amdgcn_s_barrier();
    asm volatile("" ::: "memory");

    // ---- QK^T: 4 col-tiles x 2 k-steps; kf shared across both subtiles ----
    float sv[2][4][4];
    __builtin_amdgcn_s_setprio(1);
#pragma unroll
    for (int ct = 0; ct < 4; ct++) {
      const int row = ct*16 + r16;
      bf16x8 kf0 = *(const bf16x8*)&Ks[cur][row*64 + ((g) ^ (row & 7))*8];
      bf16x8 kf1 = *(const bf16x8*)&Ks[cur][row*64 + ((4+g) ^ (row & 7))*8];
      f32x4 a0 = (f32x4){0.f,0.f,0.f,0.f}, a1 = (f32x4){0.f,0.f,0.f,0.f};
      a0 = __builtin_amdgcn_mfma_f32_16x16x32_bf16(qf[0][0], kf0, a0, 0, 0, 0);
      a0 = __builtin_amdgcn_mfma_f32_16x16x32_bf16(qf[0][1], kf1, a0, 0, 0, 0);
      a1 = __builtin_amdgcn_mfma_f32_16x16x32_bf16(qf[1][0], kf0, a1, 0, 0, 0);
      a1 = __builtin_amdgcn_mfma_f32_16x16x32_bf16(qf[1][1], kf1, a1, 0, 0, 0);
#pragma unroll
      for (int r = 0; r < 4; r++) {
        sv[0][ct][r] = a0[r]*0.125f + madd[ct];
        sv[1][ct][r] = a1[r]*0.125f + madd[ct];
      }
    }
    __builtin_amdgcn_s_setprio(0);

    // prefetch next iter's madd (drained by next iter's vmcnt(4))
    if (it + 1 < NT) {
#pragma unroll
      for (int ct = 0; ct < 4; ct++)
        madd[ct] = Mp[b*S_ + kv0 + 64 + ct*16 + r16];
    }

    // ---- lane-local softmax (defer-max THR=8, deferred sum) ----
    float lmax[8];
#pragma unroll
    for (int s = 0; s < 2; s++)
#pragma unroll
      for (int r = 0; r < 4; r++)
        lmax[s*4+r] = fmaxf(fmaxf(sv[s][0][r], sv[s][1][r]),
                            fmaxf(sv[s][2][r], sv[s][3][r]));
    bool grow = false;
#pragma unroll
    for (int i = 0; i < 8; i++) grow |= (lmax[i] > mrun[i] + 8.f);
    if (__any(grow)) {
#pragma unroll
      for (int s = 0; s < 2; s++)
#pragma unroll
        for (int r = 0; r < 4; r++) {
          const int i = s*4 + r;
          float t = lmax[i];
#pragma unroll
          for (int off = 8; off >= 1; off >>= 1) t = fmaxf(t, __shfl_xor(t, off, 16));
          float mnew = fmaxf(mrun[i], t);
          float sc = __expf(mrun[i] - mnew);
          mrun[i] = mnew;
          lsum[i] *= sc;
#pragma unroll
          for (int n = 0; n < 4; n++) po[s][n][r] *= sc;
        }
    }
#pragma unroll
    for (int s = 0; s < 2; s++)
#pragma unroll
      for (int r = 0; r < 4; r++) {
        const int i = s*4 + r;
#pragma unroll
        for (int ct = 0; ct < 4; ct++)
          sv[s][ct][r] = __expf(sv[s][ct][r] - mrun[i]);   // sv becomes P
        lsum[i] += (sv[s][0][r] + sv[s][1][r]) + (sv[s][2][r] + sv[s][3][r]);
      }

    // ---- P -> per-wave LDS (packed b64 at kv'-permuted columns) ----
#pragma unroll
    for (int s = 0; s < 2; s++)
#pragma unroll
      for (int r = 0; r < 4; r++) {
        bf16x4 pk;
#pragma unroll
        for (int ct = 0; ct < 4; ct++) pk[ct] = (bf16)sv[s][ct][r];
        *(bf16x4*)&Ps[w][(s*16 + g*4 + r)*72 + r16*4] = pk;
      }
    asm volatile("s_waitcnt lgkmcnt(0)" ::: "memory");

    // ---- PV: vf shared across both subtiles ----
    __builtin_amdgcn_s_setprio(1);
#pragma unroll
    for (int kk = 0; kk < 2; kk++) {
      bf16x8 pa0 = *(const bf16x8*)&Ps[w][(r16)*72 + kk*32 + g*8];
      bf16x8 pa1 = *(const bf16x8*)&Ps[w][(16 + r16)*72 + kk*32 + g*8];
#pragma unroll
      for (int n = 0; n < 4; n++) {
        const int row = n*16 + r16;
        bf16x8 vf = *(const bf16x8*)&Vs[cur][row*64 + ((kk*4 + g) ^ (row & 7))*8];
        po[0][n] = __builtin_amdgcn_mfma_f32_16x16x32_bf16(pa0, vf, po[0][n], 0, 0, 0);
        po[1][n] = __builtin_amdgcn_mfma_f32_16x16x32_bf16(pa1, vf, po[1][n], 0, 0, 0);
      }
    }
    __builtin_amdgcn_s_setprio(0);

    __builtin_amdgcn_s_barrier();
    asm volatile("" ::: "memory");
    cur ^= 1;
  }

  // final row-sum reduction (once)
#pragma unroll
  for (int i = 0; i < 8; i++) {
    float t = lsum[i];
#pragma unroll
    for (int off = 8; off >= 1; off >>= 1) t += __shfl_xor(t, off, 16);
    lsum[i] = t;
  }

#pragma unroll
  for (int s = 0; s < 2; s++)
#pragma unroll
    for (int n = 0; n < 4; n++)
#pragma unroll
      for (int r = 0; r < 4; r++) {
        float v = po[s][n][r] / lsum[s*4 + r];
        AO[(size_t)(b*S_ + qw + s*16 + g*4 + r)*D_ + h*64 + n*16 + r16] = (bf16)v;
      }
}

// ---------------- fused residual + LayerNorm ----------------
template<bool WB>
__global__ __launch_bounds__(256) void ln_res(
    const float* __restrict__ x, const float* __restrict__ r,
    const float* __restrict__ sc, const float* __restrict__ bi,
    float* __restrict__ y, bf16* __restrict__ yb) {
  const int row = blockIdx.x, tid = threadIdx.x;
  const size_t base = (size_t)row * D_;
  float4 a  = ((const float4*)(x + base))[tid];
  float4 b4 = ((const float4*)(r + base))[tid];
  float v[4] = {a.x + b4.x, a.y + b4.y, a.z + b4.z, a.w + b4.w};
  float s  = v[0] + v[1] + v[2] + v[3];
  float ss = v[0]*v[0] + v[1]*v[1] + v[2]*v[2] + v[3]*v[3];
#pragma unroll
  for (int off = 32; off >= 1; off >>= 1) {
    s  += __shfl_xor(s, off, 64);
    ss += __shfl_xor(ss, off, 64);
  }
  __shared__ float red[8];
  const int wv = tid >> 6;
  if ((tid & 63) == 0) { red[wv] = s; red[4 + wv] = ss; }
  __syncthreads();
  s  = red[0] + red[1] + red[2] + red[3];
  ss = red[4] + red[5] + red[6] + red[7];
  const float mu  = s * (1.0f / D_);
  const float inv = rsqrtf(ss * (1.0f / D_) - mu*mu + 1e-6f);
  float4 scv = ((const float4*)sc)[tid];
  float4 biv = ((const float4*)bi)[tid];
  float o[4];
  o[0] = (v[0]-mu)*inv*scv.x + biv.x;
  o[1] = (v[1]-mu)*inv*scv.y + biv.y;
  o[2] = (v[2]-mu)*inv*scv.z + biv.z;
  o[3] = (v[3]-mu)*inv*scv.w + biv.w;
  ((float4*)(y + base))[tid] = make_float4(o[0], o[1], o[2], o[3]);
  if (WB) {
#pragma unroll
    for (int j = 0; j < 4; j++) yb[base + tid*4 + j] = (bf16)o[j];
  }
}

// ---------------- launch ----------------
extern "C" void kernel_launch(void* const* d_in, const int* in_sizes, int n_in,
                              void* d_out, int out_size, void* d_ws, size_t ws_size,
                              hipStream_t stream) {
  const float* X    = (const float*)d_in[0];
  const int*   mask = (const int*)d_in[1];
  const float* Wq   = (const float*)d_in[2];
  const float* bq   = (const float*)d_in[3];
  const float* Wk   = (const float*)d_in[4];
  const float* bk   = (const float*)d_in[5];
  const float* Wv   = (const float*)d_in[6];
  const float* bv   = (const float*)d_in[7];
  const float* Wo   = (const float*)d_in[8];
  const float* bo   = (const float*)d_in[9];
  const float* ln0s = (const float*)d_in[10];
  const float* ln0b = (const float*)d_in[11];
  const float* W1   = (const float*)d_in[12];
  const float* b1   = (const float*)d_in[13];
  const float* W2   = (const float*)d_in[14];
  const float* b2   = (const float*)d_in[15];
  const float* ln1s = (const float*)d_in[16];
  const float* ln1b = (const float*)d_in[17];
  float* out = (float*)d_out;

  char* ws = (char*)d_ws;
  const size_t MB = 1024 * 1024;
  bf16*  Xb    = (bf16*)(ws + 0);        // 8MB
  bf16*  AO    = (bf16*)(ws + 0);        // reuse (Xb dead after QKV gemm)
  bf16*  Wqkvt = (bf16*)(ws + 8*MB);     // 6MB  [3072][1024]
  bf16*  Wot   = (bf16*)(ws + 14*MB);    // 2MB  [1024][1024]
  bf16*  W1t   = (bf16*)(ws + 16*MB);    // 8MB  [4096][1024]
  bf16*  W2t   = (bf16*)(ws + 24*MB);    // 8MB  [1024][4096]
  bf16*  QKV   = (bf16*)(ws + 32*MB);    // 24MB [4096][3072]
  bf16*  Vt    = (bf16*)(ws + 56*MB);    // 8MB  [32][64][2048]
  bf16*  FF1   = (bf16*)(ws + 32*MB);    // 32MB reuse [4096][4096]
  float* Proj  = (float*)(ws + 64*MB);   // 16MB (also FF2 out)
  float* bqkv  = (float*)(ws + 64*MB);   // 12KB, head of Proj (dead by Wo-gemm)
  float* Mp    = (float*)(ws + 64*MB + 16384);  // 16KB, head of Proj (dead by Wo-gemm)
  float* X1    = (float*)(ws + 80*MB);   // 16MB
  bf16*  X1b   = (bf16*)(ws + 96*MB);    // 8MB

  cast_f32_bf16<<<(M_*D_)/1024, 256, 0, stream>>>(X, Xb, M_*D_);
  copy3<<<12, 256, 0, stream>>>(bq, bk, bv, bqkv);
  prep_mask<<<16, 256, 0, stream>>>(mask, Mp);
  transpose_cast<<<dim3(D_/32, D_/32), 256, 0, stream>>>(Wq, Wqkvt, D_, D_);
  transpose_cast<<<dim3(D_/32, D_/32), 256, 0, stream>>>(Wk, Wqkvt + (size_t)1024*1024, D_, D_);
  transpose_cast<<<dim3(D_/32, D_/32), 256, 0, stream>>>(Wv, Wqkvt + (size_t)2048*1024, D_, D_);
  transpose_cast<<<dim3(D_/32, D_/32), 256, 0, stream>>>(Wo, Wot, D_, D_);
  transpose_cast<<<dim3(FF_/32, D_/32), 256, 0, stream>>>(W1, W1t, D_, FF_);
  transpose_cast<<<dim3(D_/32, FF_/32), 256, 0, stream>>>(W2, W2t, FF_, D_);

  gemm256<false><<<dim3(3072/256, M_/256), 512, 0, stream>>>(Xb, Wqkvt, bqkv, QKV, M_, 3072, D_);
  transpose_v<<<dim3(32, S_/64), 256, 0, stream>>>(QKV, Vt);
  attn<<<dim3(32, S_/128), 256, 0, stream>>>(QKV, Vt, Mp, AO);
  gemm_bt<true,false><<<dim3(D_/128, M_/128), 256, 0, stream>>>(AO, Wot, bo, Proj, M_, D_, D_);
  ln_res<true><<<M_, 256, 0, stream>>>(X, Proj, ln0s, ln0b, X1, X1b);
  gemm256<true><<<dim3(FF_/256, M_/256), 512, 0, stream>>>(X1b, W1t, b1, FF1, M_, FF_, D_);
  gemm_bt<true,false><<<dim3(D_/128, M_/128), 256, 0, stream>>>(FF1, W2t, b2, Proj, M_, D_, FF_);
  ln_res<false><<<M_, 256, 0, stream>>>(X1, Proj, ln1s, ln1b, out, nullptr);
}

// Round 8
// 268.740 us; speedup vs baseline: 1.5615x; 1.1323x over previous
//
#include <hip/hip_runtime.h>
#include <hip/hip_bf16.h>
#include <stdint.h>

// Problem constants
#define B_ 2
#define S_ 2048
#define D_ 1024
#define H_ 16
#define DH_ 64
#define FF_ 4096
#define M_ (B_*S_)   // 4096 tokens

typedef __bf16 bf16;
typedef __bf16 bf16x4 __attribute__((ext_vector_type(4)));
typedef __bf16 bf16x8 __attribute__((ext_vector_type(8)));
typedef float f32x4 __attribute__((ext_vector_type(4)));

// global -> LDS direct load, 16B per lane. LDS dest = wave-uniform base + lane*16.
__device__ __forceinline__ void gload_lds16(const void* g, void* l) {
  auto gp = reinterpret_cast<const __attribute__((address_space(1))) void*>(
      reinterpret_cast<uintptr_t>(g));
  auto lp = reinterpret_cast<__attribute__((address_space(3))) void*>(
      reinterpret_cast<uintptr_t>(l));
  __builtin_amdgcn_global_load_lds(gp, lp, 16, 0, 0);
}

// ---------------- prep kernels ----------------

__global__ __launch_bounds__(256) void cast_f32_bf16(
    const float* __restrict__ in, bf16* __restrict__ out, int n) {
  int i = (blockIdx.x * 256 + threadIdx.x) * 4;
  if (i < n) {
    float4 v = *(const float4*)(in + i);
    out[i+0] = (bf16)v.x; out[i+1] = (bf16)v.y;
    out[i+2] = (bf16)v.z; out[i+3] = (bf16)v.w;
  }
}

__global__ __launch_bounds__(256) void copy3(
    const float* __restrict__ a, const float* __restrict__ b,
    const float* __restrict__ c, float* __restrict__ out) {
  int i = blockIdx.x * 256 + threadIdx.x;   // 0..3071
  out[i] = i < 1024 ? a[i] : (i < 2048 ? b[i-1024] : c[i-2048]);
}

__global__ __launch_bounds__(256) void prep_mask(
    const int* __restrict__ mask, float* __restrict__ Mp) {
  int i = blockIdx.x * 256 + threadIdx.x;   // 0..4095
  Mp[i] = -10000.0f * (float)mask[i];
}

// in [K][N] f32 -> out [N][K] bf16
__global__ __launch_bounds__(256) void transpose_cast(
    const float* __restrict__ in, bf16* __restrict__ out, int K, int N) {
  __shared__ float t[32][33];
  int tx = threadIdx.x & 31, ty = threadIdx.x >> 5;  // ty 0..7
  int n0 = blockIdx.x * 32, k0 = blockIdx.y * 32;
#pragma unroll
  for (int i = 0; i < 4; i++)
    t[ty + i*8][tx] = in[(size_t)(k0 + ty + i*8) * N + n0 + tx];
  __syncthreads();
#pragma unroll
  for (int i = 0; i < 4; i++)
    out[(size_t)(n0 + ty + i*8) * K + k0 + tx] = (bf16)t[tx][ty + i*8];
}

// QKV [4096][3072] (V section) -> Vt [B*H][64][2048], kv'-permuted within
// each 64-chunk (col = (l&15)*4 + (l>>4)), matching attn's P-store layout.
__global__ __launch_bounds__(256) void transpose_v(
    const bf16* __restrict__ QKV, bf16* __restrict__ Vt) {
  __shared__ bf16 t[64][66];
  int bh = blockIdx.x, s0 = blockIdx.y * 64;
  int b = bh >> 4, h = bh & 15;
  int w = threadIdx.x >> 6, l = threadIdx.x & 63;
#pragma unroll
  for (int i = 0; i < 16; i++) {
    int sr = w*16 + i;
    t[sr][l] = QKV[(size_t)(b*S_ + s0 + sr) * 3072 + 2*D_ + h*DH_ + l];
  }
  __syncthreads();
  const int pcol = (l & 15) * 4 + (l >> 4);   // perm(l)
#pragma unroll
  for (int i = 0; i < 16; i++) {
    int dh = w*16 + i;
    Vt[((size_t)(bh*DH_ + dh)) * S_ + s0 + pcol] = t[l][dh];
  }
}

// ---------------- GEMM 128x128 split-K (for N=1024 shapes) ----------------
// m97 structure + blockIdx.z K-chunking: grid (N/128, M/128, SK), partial z
// written f32 to Cp + z*M*N; bias folded into z==0 partial. Reduction is
// fused into ln_res2. 2 blocks/CU fixes the 1-block/CU latency stall.
template<int SK>
__global__ __launch_bounds__(256) void gemm_sk(
    const bf16* __restrict__ A, const bf16* __restrict__ Bt,
    const float* __restrict__ bias, float* __restrict__ Cp,
    int M, int N, int K) {
  __shared__ bf16 As[128*32];
  __shared__ bf16 Bs[128*32];
  const int tid = threadIdx.x;
  const int w = tid >> 6, l = tid & 63;
  const int wm = w >> 1, wn = w & 1;
  const int r16 = l & 15, g = l >> 4;

  const int gx = gridDim.x, gxy = gx * gridDim.y;
  const int nwg = gxy * SK;
  const int lid = (blockIdx.z * gridDim.y + blockIdx.y) * gx + blockIdx.x;
  const int swz = (lid & 7) * (nwg >> 3) + (lid >> 3);
  const int z = swz / gxy, rem = swz % gxy;
  const int m0 = (rem / gx) * 128, n0 = (rem % gx) * 128;
  const int kc = K / SK, kb = z * kc;

  const int srow = w*16 + (l >> 2);
  const int acol8 = (l & 3) * 8;
  const bf16* ag = A + (size_t)(m0 + srow) * K + acol8;
  const bf16* bg = Bt + (size_t)(n0 + srow) * K + acol8;
  bf16* as_base = &As[(w*16) * 32];
  bf16* bs_base = &Bs[(w*16) * 32];

  f32x4 acc[4][4];
#pragma unroll
  for (int i = 0; i < 4; i++)
#pragma unroll
    for (int j = 0; j < 4; j++) acc[i][j] = (f32x4){0.f,0.f,0.f,0.f};

  for (int k0 = kb; k0 < kb + kc; k0 += 32) {
#pragma unroll
    for (int p = 0; p < 2; p++) {
      gload_lds16(ag + (size_t)(p*64) * K + k0, as_base + p*64*32);
      gload_lds16(bg + (size_t)(p*64) * K + k0, bs_base + p*64*32);
    }
    __syncthreads();
    bf16x8 af[4], bfr[4];
#pragma unroll
    for (int mi = 0; mi < 4; mi++)
      af[mi] = *(const bf16x8*)&As[(wm*64 + mi*16 + r16) * 32 + g*8];
#pragma unroll
    for (int ni = 0; ni < 4; ni++)
      bfr[ni] = *(const bf16x8*)&Bs[(wn*64 + ni*16 + r16) * 32 + g*8];
#pragma unroll
    for (int mi = 0; mi < 4; mi++)
#pragma unroll
      for (int ni = 0; ni < 4; ni++)
        acc[mi][ni] = __builtin_amdgcn_mfma_f32_16x16x32_bf16(
            af[mi], bfr[ni], acc[mi][ni], 0, 0, 0);
    __syncthreads();
  }

  float* outp = Cp + (size_t)z * M * N;
  float bvs[4];
#pragma unroll
  for (int ni = 0; ni < 4; ni++)
    bvs[ni] = (z == 0) ? bias[n0 + wn*64 + ni*16 + r16] : 0.f;
#pragma unroll
  for (int mi = 0; mi < 4; mi++)
#pragma unroll
    for (int ni = 0; ni < 4; ni++)
#pragma unroll
      for (int r = 0; r < 4; r++) {
        size_t row = (size_t)(m0 + wm*64 + mi*16 + g*4 + r);
        size_t col = (size_t)(n0 + wn*64 + ni*16 + r16);
        outp[row * N + col] = acc[mi][ni][r] + bvs[ni];
      }
}

// ---------------- GEMM 256x256, BK=64, 8 waves, phased schedule ------------
template<bool RELU>
__global__ __launch_bounds__(512) void gemm256(
    const bf16* __restrict__ A, const bf16* __restrict__ Bt,
    const float* __restrict__ bias, bf16* __restrict__ C,
    int M, int N, int K) {
  __shared__ bf16 As[2][256*64];   // 64KB
  __shared__ bf16 Bs[2][256*64];   // 64KB
  const int tid = threadIdx.x;
  const int w = tid >> 6, l = tid & 63;
  const int wm = w >> 2, wn = w & 3;     // 2 x 4 wave grid, wave tile 128x64
  const int r16 = l & 15, g = l >> 4;

  const int gx = gridDim.x;
  const int nwg = gx * gridDim.y;
  const int lid = blockIdx.y * gx + blockIdx.x;
  const int swz = (lid & 7) * (nwg >> 3) + (lid >> 3);
  const int m0 = (swz / gx) * 256, n0 = (swz % gx) * 256;

  const int srow = w*8 + (l >> 3);
  const int sch  = ((l & 7) ^ (l >> 3)) * 8;
  const bf16* ag = A  + (size_t)(m0 + srow) * K + sch;
  const bf16* bg = Bt + (size_t)(n0 + srow) * K + sch;

  f32x4 acc[8][4];
#pragma unroll
  for (int i = 0; i < 8; i++)
#pragma unroll
    for (int j = 0; j < 4; j++) acc[i][j] = (f32x4){0.f,0.f,0.f,0.f};

#pragma unroll
  for (int q = 0; q < 4; q++) {
    gload_lds16(ag + (size_t)(q*64) * K, &As[0][(q*64 + w*8) * 64]);
    gload_lds16(bg + (size_t)(q*64) * K, &Bs[0][(q*64 + w*8) * 64]);
  }
  asm volatile("s_waitcnt vmcnt(0)" ::: "memory");
  __builtin_amdgcn_s_barrier();
  asm volatile("" ::: "memory");

  const int nt = K >> 6;
  int cur = 0;
  for (int t = 0; t < nt; ++t) {
    if (t + 1 < nt) {
      const size_t k0 = (size_t)(t + 1) << 6;
#pragma unroll
      for (int q = 0; q < 4; q++) {
        gload_lds16(ag + (size_t)(q*64) * K + k0, &As[cur^1][(q*64 + w*8) * 64]);
        gload_lds16(bg + (size_t)(q*64) * K + k0, &Bs[cur^1][(q*64 + w*8) * 64]);
      }
    }

    bf16x8 af[4][2], blo[2][2], bhi[2][2];
#pragma unroll
    for (int mi = 0; mi < 4; mi++)
#pragma unroll
      for (int kk = 0; kk < 2; kk++) {
        const int row = wm*128 + mi*16 + r16;
        af[mi][kk] = *(const bf16x8*)&As[cur][row*64 + (((kk*4+g) ^ (row & 7)))*8];
      }
#pragma unroll
    for (int ni = 0; ni < 2; ni++)
#pragma unroll
      for (int kk = 0; kk < 2; kk++) {
        const int row = wn*64 + ni*16 + r16;
        blo[ni][kk] = *(const bf16x8*)&Bs[cur][row*64 + (((kk*4+g) ^ (row & 7)))*8];
      }
    __builtin_amdgcn_s_setprio(1);
#pragma unroll
    for (int mi = 0; mi < 4; mi++)
#pragma unroll
      for (int ni = 0; ni < 2; ni++)
#pragma unroll
        for (int kk = 0; kk < 2; kk++)
          acc[mi][ni] = __builtin_amdgcn_mfma_f32_16x16x32_bf16(
              af[mi][kk], blo[ni][kk], acc[mi][ni], 0, 0, 0);
    __builtin_amdgcn_s_setprio(0);
#pragma unroll
    for (int ni = 0; ni < 2; ni++)
#pragma unroll
      for (int kk = 0; kk < 2; kk++) {
        const int row = wn*64 + 32 + ni*16 + r16;
        bhi[ni][kk] = *(const bf16x8*)&Bs[cur][row*64 + (((kk*4+g) ^ (row & 7)))*8];
      }
    __builtin_amdgcn_s_setprio(1);
#pragma unroll
    for (int mi = 0; mi < 4; mi++)
#pragma unroll
      for (int ni = 0; ni < 2; ni++)
#pragma unroll
        for (int kk = 0; kk < 2; kk++)
          acc[mi][2+ni] = __builtin_amdgcn_mfma_f32_16x16x32_bf16(
              af[mi][kk], bhi[ni][kk], acc[mi][2+ni], 0, 0, 0);
    __builtin_amdgcn_s_setprio(0);
#pragma unroll
    for (int mi = 0; mi < 4; mi++)
#pragma unroll
      for (int kk = 0; kk < 2; kk++) {
        const int row = wm*128 + 64 + mi*16 + r16;
        af[mi][kk] = *(const bf16x8*)&As[cur][row*64 + (((kk*4+g) ^ (row & 7)))*8];
      }
    __builtin_amdgcn_s_setprio(1);
#pragma unroll
    for (int mi = 0; mi < 4; mi++)
#pragma unroll
      for (int ni = 0; ni < 2; ni++)
#pragma unroll
        for (int kk = 0; kk < 2; kk++)
          acc[4+mi][2+ni] = __builtin_amdgcn_mfma_f32_16x16x32_bf16(
              af[mi][kk], bhi[ni][kk], acc[4+mi][2+ni], 0, 0, 0);
    __builtin_amdgcn_s_setprio(0);
    __builtin_amdgcn_s_setprio(1);
#pragma unroll
    for (int mi = 0; mi < 4; mi++)
#pragma unroll
      for (int ni = 0; ni < 2; ni++)
#pragma unroll
        for (int kk = 0; kk < 2; kk++)
          acc[4+mi][ni] = __builtin_amdgcn_mfma_f32_16x16x32_bf16(
              af[mi][kk], blo[ni][kk], acc[4+mi][ni], 0, 0, 0);
    __builtin_amdgcn_s_setprio(0);

    asm volatile("s_waitcnt vmcnt(0)" ::: "memory");
    __builtin_amdgcn_s_barrier();
    asm volatile("" ::: "memory");
    cur ^= 1;
  }

  float bvs[4];
#pragma unroll
  for (int ni = 0; ni < 4; ni++) bvs[ni] = bias[n0 + wn*64 + ni*16 + r16];
#pragma unroll
  for (int mi = 0; mi < 8; mi++)
#pragma unroll
    for (int ni = 0; ni < 4; ni++)
#pragma unroll
      for (int r = 0; r < 4; r++) {
        float v = acc[mi][ni][r] + bvs[ni];
        if (RELU) v = fmaxf(v, 0.f);
        C[(size_t)(m0 + wm*128 + mi*16 + g*4 + r) * N +
          (n0 + wn*64 + ni*16 + r16)] = (bf16)v;
      }
}

// ---------------- flash attention ----------------
// grid (B*H, S/128); 4 waves, wave w owns 32 q rows (2 subtiles of 16).
// KVBLK=64, double-buffered staging, counted vmcnt + raw barriers, lane-local
// deferred softmax, packed-P (kv'-permuted), mask prefetch from global.
__global__ __launch_bounds__(256) void attn(
    const bf16* __restrict__ QKV, const bf16* __restrict__ Vt,
    const float* __restrict__ Mp, bf16* __restrict__ AO) {
  __shared__ bf16 Ks[2][64*64];   // [kv][dh], chunk ^= (kv&7), 16KB
  __shared__ bf16 Vs[2][64*64];   // [dh][kv'], chunk ^= (dh&7), 16KB
  __shared__ bf16 Ps[4][32*72];   // per-wave P, 32 rows, stride 72 (18KB)

  const int bh = blockIdx.x, b = bh >> 4, h = bh & 15;
  const int q0 = blockIdx.y * 128;
  const int tid = threadIdx.x, w = tid >> 6, l = tid & 63;
  const int r16 = l & 15, g = l >> 4;
  const int qw = q0 + w*32;

  bf16x8 qf[2][2];
#pragma unroll
  for (int s = 0; s < 2; s++)
#pragma unroll
    for (int kk = 0; kk < 2; kk++)
      qf[s][kk] = *(const bf16x8*)&QKV[((size_t)(b*S_ + qw + s*16 + r16))*3072
                                       + h*64 + kk*32 + g*8];

  const int srow = w*8 + (l >> 3);
  const int sch  = (l & 7) ^ (l >> 3);
  const bf16* kg = QKV + ((size_t)(b*S_) + srow)*3072 + 1024 + h*64 + sch*8;
  const bf16* vg = Vt + ((size_t)(bh*64 + srow))*S_ + sch*8;

  f32x4 po[2][4];
#pragma unroll
  for (int s = 0; s < 2; s++)
#pragma unroll
    for (int n = 0; n < 4; n++) po[s][n] = (f32x4){0.f,0.f,0.f,0.f};
  float mrun[8], lsum[8];
#pragma unroll
  for (int r = 0; r < 8; r++) { mrun[r] = -1.0e30f; lsum[r] = 0.f; }

  float madd[4];
#pragma unroll
  for (int ct = 0; ct < 4; ct++) madd[ct] = Mp[b*S_ + ct*16 + r16];
#pragma unroll
  for (int p = 0; p < 2; p++) {
    gload_lds16(kg + (size_t)(p*32)*3072, &Ks[0][(p*256 + w*64)*8]);
    gload_lds16(vg + (size_t)(p*32)*S_,   &Vs[0][(p*256 + w*64)*8]);
  }

  const int NT = S_/64;
  int cur = 0;
  for (int it = 0; it < NT; ++it) {
    const int kv0 = it * 64;
    if (it + 1 < NT) {
#pragma unroll
      for (int p = 0; p < 2; p++) {
        gload_lds16(kg + (size_t)(kv0 + 64 + p*32)*3072, &Ks[cur^1][(p*256 + w*64)*8]);
        gload_lds16(vg + (size_t)(p*32)*S_ + (kv0 + 64), &Vs[cur^1][(p*256 + w*64)*8]);
      }
      asm volatile("s_waitcnt vmcnt(4)" ::: "memory");
    } else {
      asm volatile("s_waitcnt vmcnt(0)" ::: "memory");
    }
    __builtin_amdgcn_s_barrier();
    asm volatile("" ::: "memory");

    float sv[2][4][4];
    __builtin_amdgcn_s_setprio(1);
#pragma unroll
    for (int ct = 0; ct < 4; ct++) {
      const int row = ct*16 + r16;
      bf16x8 kf0 = *(const bf16x8*)&Ks[cur][row*64 + ((g) ^ (row & 7))*8];
      bf16x8 kf1 = *(const bf16x8*)&Ks[cur][row*64 + ((4+g) ^ (row & 7))*8];
      f32x4 a0 = (f32x4){0.f,0.f,0.f,0.f}, a1 = (f32x4){0.f,0.f,0.f,0.f};
      a0 = __builtin_amdgcn_mfma_f32_16x16x32_bf16(qf[0][0], kf0, a0, 0, 0, 0);
      a0 = __builtin_amdgcn_mfma_f32_16x16x32_bf16(qf[0][1], kf1, a0, 0, 0, 0);
      a1 = __builtin_amdgcn_mfma_f32_16x16x32_bf16(qf[1][0], kf0, a1, 0, 0, 0);
      a1 = __builtin_amdgcn_mfma_f32_16x16x32_bf16(qf[1][1], kf1, a1, 0, 0, 0);
#pragma unroll
      for (int r = 0; r < 4; r++) {
        sv[0][ct][r] = a0[r]*0.125f + madd[ct];
        sv[1][ct][r] = a1[r]*0.125f + madd[ct];
      }
    }
    __builtin_amdgcn_s_setprio(0);

    if (it + 1 < NT) {
#pragma unroll
      for (int ct = 0; ct < 4; ct++)
        madd[ct] = Mp[b*S_ + kv0 + 64 + ct*16 + r16];
    }

    float lmax[8];
#pragma unroll
    for (int s = 0; s < 2; s++)
#pragma unroll
      for (int r = 0; r < 4; r++)
        lmax[s*4+r] = fmaxf(fmaxf(sv[s][0][r], sv[s][1][r]),
                            fmaxf(sv[s][2][r], sv[s][3][r]));
    bool grow = false;
#pragma unroll
    for (int i = 0; i < 8; i++) grow |= (lmax[i] > mrun[i] + 8.f);
    if (__any(grow)) {
#pragma unroll
      for (int s = 0; s < 2; s++)
#pragma unroll
        for (int r = 0; r < 4; r++) {
          const int i = s*4 + r;
          float t = lmax[i];
#pragma unroll
          for (int off = 8; off >= 1; off >>= 1) t = fmaxf(t, __shfl_xor(t, off, 16));
          float mnew = fmaxf(mrun[i], t);
          float sc = __expf(mrun[i] - mnew);
          mrun[i] = mnew;
          lsum[i] *= sc;
#pragma unroll
          for (int n = 0; n < 4; n++) po[s][n][r] *= sc;
        }
    }
#pragma unroll
    for (int s = 0; s < 2; s++)
#pragma unroll
      for (int r = 0; r < 4; r++) {
        const int i = s*4 + r;
#pragma unroll
        for (int ct = 0; ct < 4; ct++)
          sv[s][ct][r] = __expf(sv[s][ct][r] - mrun[i]);   // sv becomes P
        lsum[i] += (sv[s][0][r] + sv[s][1][r]) + (sv[s][2][r] + sv[s][3][r]);
      }

#pragma unroll
    for (int s = 0; s < 2; s++)
#pragma unroll
      for (int r = 0; r < 4; r++) {
        bf16x4 pk;
#pragma unroll
        for (int ct = 0; ct < 4; ct++) pk[ct] = (bf16)sv[s][ct][r];
        *(bf16x4*)&Ps[w][(s*16 + g*4 + r)*72 + r16*4] = pk;
      }
    asm volatile("s_waitcnt lgkmcnt(0)" ::: "memory");

    __builtin_amdgcn_s_setprio(1);
#pragma unroll
    for (int kk = 0; kk < 2; kk++) {
      bf16x8 pa0 = *(const bf16x8*)&Ps[w][(r16)*72 + kk*32 + g*8];
      bf16x8 pa1 = *(const bf16x8*)&Ps[w][(16 + r16)*72 + kk*32 + g*8];
#pragma unroll
      for (int n = 0; n < 4; n++) {
        const int row = n*16 + r16;
        bf16x8 vf = *(const bf16x8*)&Vs[cur][row*64 + ((kk*4 + g) ^ (row & 7))*8];
        po[0][n] = __builtin_amdgcn_mfma_f32_16x16x32_bf16(pa0, vf, po[0][n], 0, 0, 0);
        po[1][n] = __builtin_amdgcn_mfma_f32_16x16x32_bf16(pa1, vf, po[1][n], 0, 0, 0);
      }
    }
    __builtin_amdgcn_s_setprio(0);

    __builtin_amdgcn_s_barrier();
    asm volatile("" ::: "memory");
    cur ^= 1;
  }

#pragma unroll
  for (int i = 0; i < 8; i++) {
    float t = lsum[i];
#pragma unroll
    for (int off = 8; off >= 1; off >>= 1) t += __shfl_xor(t, off, 16);
    lsum[i] = t;
  }

#pragma unroll
  for (int s = 0; s < 2; s++)
#pragma unroll
    for (int n = 0; n < 4; n++)
#pragma unroll
      for (int r = 0; r < 4; r++) {
        float v = po[s][n][r] / lsum[s*4 + r];
        AO[(size_t)(b*S_ + qw + s*16 + g*4 + r)*D_ + h*64 + n*16 + r16] = (bf16)v;
      }
}

// ---------------- fused residual + 2-partial reduce + LayerNorm ------------
// v = x + p0 + p1 (p0 carries the gemm bias); XF32 selects x dtype;
// OUTF32: write f32 y, else write bf16 yb.
template<bool XF32, bool OUTF32>
__global__ __launch_bounds__(256) void ln_res2(
    const void* __restrict__ xp, const float* __restrict__ p0,
    const float* __restrict__ p1, const float* __restrict__ sc,
    const float* __restrict__ bi, float* __restrict__ y,
    bf16* __restrict__ yb) {
  const int row = blockIdx.x, tid = threadIdx.x;
  const size_t base = (size_t)row * D_;
  float xv[4];
  if (XF32) {
    float4 a = ((const float4*)((const float*)xp + base))[tid];
    xv[0] = a.x; xv[1] = a.y; xv[2] = a.z; xv[3] = a.w;
  } else {
    bf16x4 a = ((const bf16x4*)((const bf16*)xp + base))[tid];
#pragma unroll
    for (int j = 0; j < 4; j++) xv[j] = (float)a[j];
  }
  float4 a0 = ((const float4*)(p0 + base))[tid];
  float4 a1 = ((const float4*)(p1 + base))[tid];
  float v[4] = {xv[0] + a0.x + a1.x, xv[1] + a0.y + a1.y,
                xv[2] + a0.z + a1.z, xv[3] + a0.w + a1.w};
  float s  = v[0] + v[1] + v[2] + v[3];
  float ss = v[0]*v[0] + v[1]*v[1] + v[2]*v[2] + v[3]*v[3];
#pragma unroll
  for (int off = 32; off >= 1; off >>= 1) {
    s  += __shfl_xor(s, off, 64);
    ss += __shfl_xor(ss, off, 64);
  }
  __shared__ float red[8];
  const int wv = tid >> 6;
  if ((tid & 63) == 0) { red[wv] = s; red[4 + wv] = ss; }
  __syncthreads();
  s  = red[0] + red[1] + red[2] + red[3];
  ss = red[4] + red[5] + red[6] + red[7];
  const float mu  = s * (1.0f / D_);
  const float inv = rsqrtf(ss * (1.0f / D_) - mu*mu + 1e-6f);
  float4 scv = ((const float4*)sc)[tid];
  float4 biv = ((const float4*)bi)[tid];
  float o[4];
  o[0] = (v[0]-mu)*inv*scv.x + biv.x;
  o[1] = (v[1]-mu)*inv*scv.y + biv.y;
  o[2] = (v[2]-mu)*inv*scv.z + biv.z;
  o[3] = (v[3]-mu)*inv*scv.w + biv.w;
  if (OUTF32) {
    ((float4*)(y + base))[tid] = make_float4(o[0], o[1], o[2], o[3]);
  } else {
    bf16x4 ob;
#pragma unroll
    for (int j = 0; j < 4; j++) ob[j] = (bf16)o[j];
    *(bf16x4*)&yb[base + tid*4] = ob;
  }
}

// ---------------- launch ----------------
extern "C" void kernel_launch(void* const* d_in, const int* in_sizes, int n_in,
                              void* d_out, int out_size, void* d_ws, size_t ws_size,
                              hipStream_t stream) {
  const float* X    = (const float*)d_in[0];
  const int*   mask = (const int*)d_in[1];
  const float* Wq   = (const float*)d_in[2];
  const float* bq   = (const float*)d_in[3];
  const float* Wk   = (const float*)d_in[4];
  const float* bk   = (const float*)d_in[5];
  const float* Wv   = (const float*)d_in[6];
  const float* bv   = (const float*)d_in[7];
  const float* Wo   = (const float*)d_in[8];
  const float* bo   = (const float*)d_in[9];
  const float* ln0s = (const float*)d_in[10];
  const float* ln0b = (const float*)d_in[11];
  const float* W1   = (const float*)d_in[12];
  const float* b1   = (const float*)d_in[13];
  const float* W2   = (const float*)d_in[14];
  const float* b2   = (const float*)d_in[15];
  const float* ln1s = (const float*)d_in[16];
  const float* ln1b = (const float*)d_in[17];
  float* out = (float*)d_out;

  // workspace layout (96 MB), lifetime-checked reuse:
  //  [0,8)    Xb -> AO -> X1b
  //  [8,16)   Wqkvt(6) + Wot(2)
  //  [16,24)  W1t   [24,32) W2t
  //  [32,64)  QKV(24)+Vt(8) -> FF1(32)
  //  [64,80)  bqkv+Mp (head) -> WoP0 -> F2P0
  //  [80,96)  WoP1 -> F2P1
  char* ws = (char*)d_ws;
  const size_t MB = 1024 * 1024;
  bf16*  Xb    = (bf16*)(ws + 0);        // 8MB
  bf16*  AO    = (bf16*)(ws + 0);        // reuse
  bf16*  X1b   = (bf16*)(ws + 0);        // reuse (AO dead after Wo gemm)
  bf16*  Wqkvt = (bf16*)(ws + 8*MB);     // 6MB  [3072][1024]
  bf16*  Wot   = (bf16*)(ws + 14*MB);    // 2MB  [1024][1024]
  bf16*  W1t   = (bf16*)(ws + 16*MB);    // 8MB  [4096][1024]
  bf16*  W2t   = (bf16*)(ws + 24*MB);    // 8MB  [1024][4096]
  bf16*  QKV   = (bf16*)(ws + 32*MB);    // 24MB [4096][3072]
  bf16*  Vt    = (bf16*)(ws + 56*MB);    // 8MB  [32][64][2048]
  bf16*  FF1   = (bf16*)(ws + 32*MB);    // 32MB reuse [4096][4096]
  float* P0    = (float*)(ws + 64*MB);   // 16MB partial 0 (Wo then FF2)
  float* P1    = (float*)(ws + 80*MB);   // 16MB partial 1
  float* bqkv  = (float*)(ws + 64*MB);   // 12KB head of P0 (dead by Wo gemm)
  float* Mp    = (float*)(ws + 64*MB + 16384);  // 16KB head of P0

  cast_f32_bf16<<<(M_*D_)/1024, 256, 0, stream>>>(X, Xb, M_*D_);
  copy3<<<12, 256, 0, stream>>>(bq, bk, bv, bqkv);
  prep_mask<<<16, 256, 0, stream>>>(mask, Mp);
  transpose_cast<<<dim3(D_/32, D_/32), 256, 0, stream>>>(Wq, Wqkvt, D_, D_);
  transpose_cast<<<dim3(D_/32, D_/32), 256, 0, stream>>>(Wk, Wqkvt + (size_t)1024*1024, D_, D_);
  transpose_cast<<<dim3(D_/32, D_/32), 256, 0, stream>>>(Wv, Wqkvt + (size_t)2048*1024, D_, D_);
  transpose_cast<<<dim3(D_/32, D_/32), 256, 0, stream>>>(Wo, Wot, D_, D_);
  transpose_cast<<<dim3(FF_/32, D_/32), 256, 0, stream>>>(W1, W1t, D_, FF_);
  transpose_cast<<<dim3(D_/32, FF_/32), 256, 0, stream>>>(W2, W2t, FF_, D_);

  gemm256<false><<<dim3(3072/256, M_/256), 512, 0, stream>>>(Xb, Wqkvt, bqkv, QKV, M_, 3072, D_);
  transpose_v<<<dim3(32, S_/64), 256, 0, stream>>>(QKV, Vt);
  attn<<<dim3(32, S_/128), 256, 0, stream>>>(QKV, Vt, Mp, AO);
  gemm_sk<2><<<dim3(D_/128, M_/128, 2), 256, 0, stream>>>(AO, Wot, bo, P0, M_, D_, D_);
  ln_res2<true,false><<<M_, 256, 0, stream>>>(X, P0, P1, ln0s, ln0b, nullptr, X1b);
  gemm256<true><<<dim3(FF_/256, M_/256), 512, 0, stream>>>(X1b, W1t, b1, FF1, M_, FF_, D_);
  gemm_sk<2><<<dim3(D_/128, M_/128, 2), 256, 0, stream>>>(FF1, W2t, b2, P0, M_, D_, FF_);
  ln_res2<false,true><<<M_, 256, 0, stream>>>(X1b, P0, P1, ln1s, ln1b, out, nullptr);
}

// Round 9
// 243.408 us; speedup vs baseline: 1.7240x; 1.1041x over previous
//
#include <hip/hip_runtime.h>
#include <hip/hip_bf16.h>
#include <stdint.h>

// Problem constants
#define B_ 2
#define S_ 2048
#define D_ 1024
#define H_ 16
#define DH_ 64
#define FF_ 4096
#define M_ (B_*S_)   // 4096 tokens

typedef __bf16 bf16;
typedef __bf16 bf16x4 __attribute__((ext_vector_type(4)));
typedef __bf16 bf16x8 __attribute__((ext_vector_type(8)));
typedef float f32x4 __attribute__((ext_vector_type(4)));

#define LOG2E 1.44269504f

__device__ __forceinline__ float fexp2(float x) {
#if __has_builtin(__builtin_amdgcn_exp2f)
  return __builtin_amdgcn_exp2f(x);
#else
  return exp2f(x);
#endif
}

// global -> LDS direct load, 16B per lane. LDS dest = wave-uniform base + lane*16.
__device__ __forceinline__ void gload_lds16(const void* g, void* l) {
  auto gp = reinterpret_cast<const __attribute__((address_space(1))) void*>(
      reinterpret_cast<uintptr_t>(g));
  auto lp = reinterpret_cast<__attribute__((address_space(3))) void*>(
      reinterpret_cast<uintptr_t>(l));
  __builtin_amdgcn_global_load_lds(gp, lp, 16, 0, 0);
}

// ---------------- prep kernels ----------------

__global__ __launch_bounds__(256) void cast_f32_bf16(
    const float* __restrict__ in, bf16* __restrict__ out, int n) {
  int i = (blockIdx.x * 256 + threadIdx.x) * 4;
  if (i < n) {
    float4 v = *(const float4*)(in + i);
    out[i+0] = (bf16)v.x; out[i+1] = (bf16)v.y;
    out[i+2] = (bf16)v.z; out[i+3] = (bf16)v.w;
  }
}

__global__ __launch_bounds__(256) void copy3(
    const float* __restrict__ a, const float* __restrict__ b,
    const float* __restrict__ c, float* __restrict__ out) {
  int i = blockIdx.x * 256 + threadIdx.x;   // 0..3071
  out[i] = i < 1024 ? a[i] : (i < 2048 ? b[i-1024] : c[i-2048]);
}

// mask additive term pre-scaled by log2(e): attn works in exp2 domain.
__global__ __launch_bounds__(256) void prep_mask(
    const int* __restrict__ mask, float* __restrict__ Mp) {
  int i = blockIdx.x * 256 + threadIdx.x;   // 0..4095
  Mp[i] = (-10000.0f * LOG2E) * (float)mask[i];
}

// in [K][N] f32 -> out [N][K] bf16
__global__ __launch_bounds__(256) void transpose_cast(
    const float* __restrict__ in, bf16* __restrict__ out, int K, int N) {
  __shared__ float t[32][33];
  int tx = threadIdx.x & 31, ty = threadIdx.x >> 5;  // ty 0..7
  int n0 = blockIdx.x * 32, k0 = blockIdx.y * 32;
#pragma unroll
  for (int i = 0; i < 4; i++)
    t[ty + i*8][tx] = in[(size_t)(k0 + ty + i*8) * N + n0 + tx];
  __syncthreads();
#pragma unroll
  for (int i = 0; i < 4; i++)
    out[(size_t)(n0 + ty + i*8) * K + k0 + tx] = (bf16)t[tx][ty + i*8];
}

// QKV [4096][3072] (V section) -> Vt [B*H][64][2048], kv'-permuted within
// each 64-chunk (col = (l&15)*4 + (l>>4)), matching attn's P-store layout.
__global__ __launch_bounds__(256) void transpose_v(
    const bf16* __restrict__ QKV, bf16* __restrict__ Vt) {
  __shared__ bf16 t[64][66];
  int bh = blockIdx.x, s0 = blockIdx.y * 64;
  int b = bh >> 4, h = bh & 15;
  int w = threadIdx.x >> 6, l = threadIdx.x & 63;
#pragma unroll
  for (int i = 0; i < 16; i++) {
    int sr = w*16 + i;
    t[sr][l] = QKV[(size_t)(b*S_ + s0 + sr) * 3072 + 2*D_ + h*DH_ + l];
  }
  __syncthreads();
  const int pcol = (l & 15) * 4 + (l >> 4);   // perm(l)
#pragma unroll
  for (int i = 0; i < 16; i++) {
    int dh = w*16 + i;
    Vt[((size_t)(bh*DH_ + dh)) * S_ + s0 + pcol] = t[l][dh];
  }
}

// ---------------- GEMM 128x128 split-K, double-buffered ----------------
// m97 fragment layout + gemm256-style schedule: issue next K-step's loads
// BEFORE the ds_read+MFMA phase (latency cover), single vmcnt(0)+s_barrier
// per step. Partial z written f32 to Cp + z*M*N; bias folded into z==0.
template<int SK>
__global__ __launch_bounds__(256) void gemm_sk(
    const bf16* __restrict__ A, const bf16* __restrict__ Bt,
    const float* __restrict__ bias, float* __restrict__ Cp,
    int M, int N, int K) {
  __shared__ bf16 As[2][128*32];
  __shared__ bf16 Bs[2][128*32];
  const int tid = threadIdx.x;
  const int w = tid >> 6, l = tid & 63;
  const int wm = w >> 1, wn = w & 1;
  const int r16 = l & 15, g = l >> 4;

  const int gx = gridDim.x, gxy = gx * gridDim.y;
  const int nwg = gxy * SK;
  const int lid = (blockIdx.z * gridDim.y + blockIdx.y) * gx + blockIdx.x;
  const int swz = (lid & 7) * (nwg >> 3) + (lid >> 3);
  const int z = swz / gxy, rem = swz % gxy;
  const int m0 = (rem / gx) * 128, n0 = (rem % gx) * 128;
  const int kc = K / SK, kb = z * kc;

  const int srow = w*16 + (l >> 2);
  const int acol8 = (l & 3) * 8;
  const bf16* ag = A + (size_t)(m0 + srow) * K + acol8;
  const bf16* bg = Bt + (size_t)(n0 + srow) * K + acol8;

  f32x4 acc[4][4];
#pragma unroll
  for (int i = 0; i < 4; i++)
#pragma unroll
    for (int j = 0; j < 4; j++) acc[i][j] = (f32x4){0.f,0.f,0.f,0.f};

  // prologue: stage K-step 0 into buf 0
#pragma unroll
  for (int p = 0; p < 2; p++) {
    gload_lds16(ag + (size_t)(p*64) * K + kb, &As[0][(p*64 + w*16) * 32]);
    gload_lds16(bg + (size_t)(p*64) * K + kb, &Bs[0][(p*64 + w*16) * 32]);
  }
  asm volatile("s_waitcnt vmcnt(0)" ::: "memory");
  __builtin_amdgcn_s_barrier();
  asm volatile("" ::: "memory");

  const int nt = kc >> 5;
  int cur = 0;
  for (int t = 0; t < nt; ++t) {
    if (t + 1 < nt) {
      const int k0 = kb + (t + 1) * 32;
#pragma unroll
      for (int p = 0; p < 2; p++) {
        gload_lds16(ag + (size_t)(p*64) * K + k0, &As[cur^1][(p*64 + w*16) * 32]);
        gload_lds16(bg + (size_t)(p*64) * K + k0, &Bs[cur^1][(p*64 + w*16) * 32]);
      }
    }
    bf16x8 af[4], bfr[4];
#pragma unroll
    for (int mi = 0; mi < 4; mi++)
      af[mi] = *(const bf16x8*)&As[cur][(wm*64 + mi*16 + r16) * 32 + g*8];
#pragma unroll
    for (int ni = 0; ni < 4; ni++)
      bfr[ni] = *(const bf16x8*)&Bs[cur][(wn*64 + ni*16 + r16) * 32 + g*8];
    __builtin_amdgcn_s_setprio(1);
#pragma unroll
    for (int mi = 0; mi < 4; mi++)
#pragma unroll
      for (int ni = 0; ni < 4; ni++)
        acc[mi][ni] = __builtin_amdgcn_mfma_f32_16x16x32_bf16(
            af[mi], bfr[ni], acc[mi][ni], 0, 0, 0);
    __builtin_amdgcn_s_setprio(0);

    asm volatile("s_waitcnt vmcnt(0)" ::: "memory");
    __builtin_amdgcn_s_barrier();
    asm volatile("" ::: "memory");
    cur ^= 1;
  }

  float* outp = Cp + (size_t)z * M * N;
  float bvs[4];
#pragma unroll
  for (int ni = 0; ni < 4; ni++)
    bvs[ni] = (z == 0) ? bias[n0 + wn*64 + ni*16 + r16] : 0.f;
#pragma unroll
  for (int mi = 0; mi < 4; mi++)
#pragma unroll
    for (int ni = 0; ni < 4; ni++)
#pragma unroll
      for (int r = 0; r < 4; r++) {
        size_t row = (size_t)(m0 + wm*64 + mi*16 + g*4 + r);
        size_t col = (size_t)(n0 + wn*64 + ni*16 + r16);
        outp[row * N + col] = acc[mi][ni][r] + bvs[ni];
      }
}

// ---------------- GEMM 256x256, BK=64, 8 waves, phased schedule ------------
template<bool RELU>
__global__ __launch_bounds__(512) void gemm256(
    const bf16* __restrict__ A, const bf16* __restrict__ Bt,
    const float* __restrict__ bias, bf16* __restrict__ C,
    int M, int N, int K) {
  __shared__ bf16 As[2][256*64];   // 64KB
  __shared__ bf16 Bs[2][256*64];   // 64KB
  const int tid = threadIdx.x;
  const int w = tid >> 6, l = tid & 63;
  const int wm = w >> 2, wn = w & 3;     // 2 x 4 wave grid, wave tile 128x64
  const int r16 = l & 15, g = l >> 4;

  const int gx = gridDim.x;
  const int nwg = gx * gridDim.y;
  const int lid = blockIdx.y * gx + blockIdx.x;
  const int swz = (lid & 7) * (nwg >> 3) + (lid >> 3);
  const int m0 = (swz / gx) * 256, n0 = (swz % gx) * 256;

  const int srow = w*8 + (l >> 3);
  const int sch  = ((l & 7) ^ (l >> 3)) * 8;
  const bf16* ag = A  + (size_t)(m0 + srow) * K + sch;
  const bf16* bg = Bt + (size_t)(n0 + srow) * K + sch;

  f32x4 acc[8][4];
#pragma unroll
  for (int i = 0; i < 8; i++)
#pragma unroll
    for (int j = 0; j < 4; j++) acc[i][j] = (f32x4){0.f,0.f,0.f,0.f};

#pragma unroll
  for (int q = 0; q < 4; q++) {
    gload_lds16(ag + (size_t)(q*64) * K, &As[0][(q*64 + w*8) * 64]);
    gload_lds16(bg + (size_t)(q*64) * K, &Bs[0][(q*64 + w*8) * 64]);
  }
  asm volatile("s_waitcnt vmcnt(0)" ::: "memory");
  __builtin_amdgcn_s_barrier();
  asm volatile("" ::: "memory");

  const int nt = K >> 6;
  int cur = 0;
  for (int t = 0; t < nt; ++t) {
    if (t + 1 < nt) {
      const size_t k0 = (size_t)(t + 1) << 6;
#pragma unroll
      for (int q = 0; q < 4; q++) {
        gload_lds16(ag + (size_t)(q*64) * K + k0, &As[cur^1][(q*64 + w*8) * 64]);
        gload_lds16(bg + (size_t)(q*64) * K + k0, &Bs[cur^1][(q*64 + w*8) * 64]);
      }
    }

    bf16x8 af[4][2], blo[2][2], bhi[2][2];
#pragma unroll
    for (int mi = 0; mi < 4; mi++)
#pragma unroll
      for (int kk = 0; kk < 2; kk++) {
        const int row = wm*128 + mi*16 + r16;
        af[mi][kk] = *(const bf16x8*)&As[cur][row*64 + (((kk*4+g) ^ (row & 7)))*8];
      }
#pragma unroll
    for (int ni = 0; ni < 2; ni++)
#pragma unroll
      for (int kk = 0; kk < 2; kk++) {
        const int row = wn*64 + ni*16 + r16;
        blo[ni][kk] = *(const bf16x8*)&Bs[cur][row*64 + (((kk*4+g) ^ (row & 7)))*8];
      }
    __builtin_amdgcn_s_setprio(1);
#pragma unroll
    for (int mi = 0; mi < 4; mi++)
#pragma unroll
      for (int ni = 0; ni < 2; ni++)
#pragma unroll
        for (int kk = 0; kk < 2; kk++)
          acc[mi][ni] = __builtin_amdgcn_mfma_f32_16x16x32_bf16(
              af[mi][kk], blo[ni][kk], acc[mi][ni], 0, 0, 0);
    __builtin_amdgcn_s_setprio(0);
#pragma unroll
    for (int ni = 0; ni < 2; ni++)
#pragma unroll
      for (int kk = 0; kk < 2; kk++) {
        const int row = wn*64 + 32 + ni*16 + r16;
        bhi[ni][kk] = *(const bf16x8*)&Bs[cur][row*64 + (((kk*4+g) ^ (row & 7)))*8];
      }
    __builtin_amdgcn_s_setprio(1);
#pragma unroll
    for (int mi = 0; mi < 4; mi++)
#pragma unroll
      for (int ni = 0; ni < 2; ni++)
#pragma unroll
        for (int kk = 0; kk < 2; kk++)
          acc[mi][2+ni] = __builtin_amdgcn_mfma_f32_16x16x32_bf16(
              af[mi][kk], bhi[ni][kk], acc[mi][2+ni], 0, 0, 0);
    __builtin_amdgcn_s_setprio(0);
#pragma unroll
    for (int mi = 0; mi < 4; mi++)
#pragma unroll
      for (int kk = 0; kk < 2; kk++) {
        const int row = wm*128 + 64 + mi*16 + r16;
        af[mi][kk] = *(const bf16x8*)&As[cur][row*64 + (((kk*4+g) ^ (row & 7)))*8];
      }
    __builtin_amdgcn_s_setprio(1);
#pragma unroll
    for (int mi = 0; mi < 4; mi++)
#pragma unroll
      for (int ni = 0; ni < 2; ni++)
#pragma unroll
        for (int kk = 0; kk < 2; kk++)
          acc[4+mi][2+ni] = __builtin_amdgcn_mfma_f32_16x16x32_bf16(
              af[mi][kk], bhi[ni][kk], acc[4+mi][2+ni], 0, 0, 0);
    __builtin_amdgcn_s_setprio(0);
    __builtin_amdgcn_s_setprio(1);
#pragma unroll
    for (int mi = 0; mi < 4; mi++)
#pragma unroll
      for (int ni = 0; ni < 2; ni++)
#pragma unroll
        for (int kk = 0; kk < 2; kk++)
          acc[4+mi][ni] = __builtin_amdgcn_mfma_f32_16x16x32_bf16(
              af[mi][kk], blo[ni][kk], acc[4+mi][ni], 0, 0, 0);
    __builtin_amdgcn_s_setprio(0);

    asm volatile("s_waitcnt vmcnt(0)" ::: "memory");
    __builtin_amdgcn_s_barrier();
    asm volatile("" ::: "memory");
    cur ^= 1;
  }

  float bvs[4];
#pragma unroll
  for (int ni = 0; ni < 4; ni++) bvs[ni] = bias[n0 + wn*64 + ni*16 + r16];
#pragma unroll
  for (int mi = 0; mi < 8; mi++)
#pragma unroll
    for (int ni = 0; ni < 4; ni++)
#pragma unroll
      for (int r = 0; r < 4; r++) {
        float v = acc[mi][ni][r] + bvs[ni];
        if (RELU) v = fmaxf(v, 0.f);
        C[(size_t)(m0 + wm*128 + mi*16 + g*4 + r) * N +
          (n0 + wn*64 + ni*16 + r16)] = (bf16)v;
      }
}

// ---------------- flash attention ----------------
// grid (B*H, S/128); 4 waves, wave w owns 32 q rows (2 subtiles of 16).
// KVBLK=64, double-buffered staging, counted vmcnt + raw barriers, lane-local
// deferred softmax in exp2 domain (scale & mask pre-multiplied by log2e),
// packed-P (kv'-permuted), mask prefetch from global.
__global__ __launch_bounds__(256) void attn(
    const bf16* __restrict__ QKV, const bf16* __restrict__ Vt,
    const float* __restrict__ Mp, bf16* __restrict__ AO) {
  __shared__ bf16 Ks[2][64*64];   // [kv][dh], chunk ^= (kv&7), 16KB
  __shared__ bf16 Vs[2][64*64];   // [dh][kv'], chunk ^= (dh&7), 16KB
  __shared__ bf16 Ps[4][32*72];   // per-wave P, 32 rows, stride 72 (18KB)

  const float SC2 = 0.125f * LOG2E;
  const int bh = blockIdx.x, b = bh >> 4, h = bh & 15;
  const int q0 = blockIdx.y * 128;
  const int tid = threadIdx.x, w = tid >> 6, l = tid & 63;
  const int r16 = l & 15, g = l >> 4;
  const int qw = q0 + w*32;

  bf16x8 qf[2][2];
#pragma unroll
  for (int s = 0; s < 2; s++)
#pragma unroll
    for (int kk = 0; kk < 2; kk++)
      qf[s][kk] = *(const bf16x8*)&QKV[((size_t)(b*S_ + qw + s*16 + r16))*3072
                                       + h*64 + kk*32 + g*8];

  const int srow = w*8 + (l >> 3);
  const int sch  = (l & 7) ^ (l >> 3);
  const bf16* kg = QKV + ((size_t)(b*S_) + srow)*3072 + 1024 + h*64 + sch*8;
  const bf16* vg = Vt + ((size_t)(bh*64 + srow))*S_ + sch*8;

  f32x4 po[2][4];
#pragma unroll
  for (int s = 0; s < 2; s++)
#pragma unroll
    for (int n = 0; n < 4; n++) po[s][n] = (f32x4){0.f,0.f,0.f,0.f};
  float mrun[8], lsum[8];
#pragma unroll
  for (int r = 0; r < 8; r++) { mrun[r] = -1.0e30f; lsum[r] = 0.f; }

  float madd[4];
#pragma unroll
  for (int ct = 0; ct < 4; ct++) madd[ct] = Mp[b*S_ + ct*16 + r16];
#pragma unroll
  for (int p = 0; p < 2; p++) {
    gload_lds16(kg + (size_t)(p*32)*3072, &Ks[0][(p*256 + w*64)*8]);
    gload_lds16(vg + (size_t)(p*32)*S_,   &Vs[0][(p*256 + w*64)*8]);
  }

  const int NT = S_/64;
  int cur = 0;
  for (int it = 0; it < NT; ++it) {
    const int kv0 = it * 64;
    if (it + 1 < NT) {
#pragma unroll
      for (int p = 0; p < 2; p++) {
        gload_lds16(kg + (size_t)(kv0 + 64 + p*32)*3072, &Ks[cur^1][(p*256 + w*64)*8]);
        gload_lds16(vg + (size_t)(p*32)*S_ + (kv0 + 64), &Vs[cur^1][(p*256 + w*64)*8]);
      }
      asm volatile("s_waitcnt vmcnt(4)" ::: "memory");
    } else {
      asm volatile("s_waitcnt vmcnt(0)" ::: "memory");
    }
    __builtin_amdgcn_s_barrier();
    asm volatile("" ::: "memory");

    float sv[2][4][4];
    __builtin_amdgcn_s_setprio(1);
#pragma unroll
    for (int ct = 0; ct < 4; ct++) {
      const int row = ct*16 + r16;
      bf16x8 kf0 = *(const bf16x8*)&Ks[cur][row*64 + ((g) ^ (row & 7))*8];
      bf16x8 kf1 = *(const bf16x8*)&Ks[cur][row*64 + ((4+g) ^ (row & 7))*8];
      f32x4 a0 = (f32x4){0.f,0.f,0.f,0.f}, a1 = (f32x4){0.f,0.f,0.f,0.f};
      a0 = __builtin_amdgcn_mfma_f32_16x16x32_bf16(qf[0][0], kf0, a0, 0, 0, 0);
      a0 = __builtin_amdgcn_mfma_f32_16x16x32_bf16(qf[0][1], kf1, a0, 0, 0, 0);
      a1 = __builtin_amdgcn_mfma_f32_16x16x32_bf16(qf[1][0], kf0, a1, 0, 0, 0);
      a1 = __builtin_amdgcn_mfma_f32_16x16x32_bf16(qf[1][1], kf1, a1, 0, 0, 0);
#pragma unroll
      for (int r = 0; r < 4; r++) {
        sv[0][ct][r] = a0[r]*SC2 + madd[ct];
        sv[1][ct][r] = a1[r]*SC2 + madd[ct];
      }
    }
    __builtin_amdgcn_s_setprio(0);

    if (it + 1 < NT) {
#pragma unroll
      for (int ct = 0; ct < 4; ct++)
        madd[ct] = Mp[b*S_ + kv0 + 64 + ct*16 + r16];
    }

    float lmax[8];
#pragma unroll
    for (int s = 0; s < 2; s++)
#pragma unroll
      for (int r = 0; r < 4; r++)
        lmax[s*4+r] = fmaxf(fmaxf(sv[s][0][r], sv[s][1][r]),
                            fmaxf(sv[s][2][r], sv[s][3][r]));
    bool grow = false;
#pragma unroll
    for (int i = 0; i < 8; i++) grow |= (lmax[i] > mrun[i] + 8.f);
    if (__any(grow)) {
#pragma unroll
      for (int s = 0; s < 2; s++)
#pragma unroll
        for (int r = 0; r < 4; r++) {
          const int i = s*4 + r;
          float t = lmax[i];
#pragma unroll
          for (int off = 8; off >= 1; off >>= 1) t = fmaxf(t, __shfl_xor(t, off, 16));
          float mnew = fmaxf(mrun[i], t);
          float sc = fexp2(mrun[i] - mnew);
          mrun[i] = mnew;
          lsum[i] *= sc;
#pragma unroll
          for (int n = 0; n < 4; n++) po[s][n][r] *= sc;
        }
    }
#pragma unroll
    for (int s = 0; s < 2; s++)
#pragma unroll
      for (int r = 0; r < 4; r++) {
        const int i = s*4 + r;
#pragma unroll
        for (int ct = 0; ct < 4; ct++)
          sv[s][ct][r] = fexp2(sv[s][ct][r] - mrun[i]);   // sv becomes P
        lsum[i] += (sv[s][0][r] + sv[s][1][r]) + (sv[s][2][r] + sv[s][3][r]);
      }

#pragma unroll
    for (int s = 0; s < 2; s++)
#pragma unroll
      for (int r = 0; r < 4; r++) {
        bf16x4 pk;
#pragma unroll
        for (int ct = 0; ct < 4; ct++) pk[ct] = (bf16)sv[s][ct][r];
        *(bf16x4*)&Ps[w][(s*16 + g*4 + r)*72 + r16*4] = pk;
      }
    asm volatile("s_waitcnt lgkmcnt(0)" ::: "memory");

    __builtin_amdgcn_s_setprio(1);
#pragma unroll
    for (int kk = 0; kk < 2; kk++) {
      bf16x8 pa0 = *(const bf16x8*)&Ps[w][(r16)*72 + kk*32 + g*8];
      bf16x8 pa1 = *(const bf16x8*)&Ps[w][(16 + r16)*72 + kk*32 + g*8];
#pragma unroll
      for (int n = 0; n < 4; n++) {
        const int row = n*16 + r16;
        bf16x8 vf = *(const bf16x8*)&Vs[cur][row*64 + ((kk*4 + g) ^ (row & 7))*8];
        po[0][n] = __builtin_amdgcn_mfma_f32_16x16x32_bf16(pa0, vf, po[0][n], 0, 0, 0);
        po[1][n] = __builtin_amdgcn_mfma_f32_16x16x32_bf16(pa1, vf, po[1][n], 0, 0, 0);
      }
    }
    __builtin_amdgcn_s_setprio(0);

    __builtin_amdgcn_s_barrier();
    asm volatile("" ::: "memory");
    cur ^= 1;
  }

#pragma unroll
  for (int i = 0; i < 8; i++) {
    float t = lsum[i];
#pragma unroll
    for (int off = 8; off >= 1; off >>= 1) t += __shfl_xor(t, off, 16);
    lsum[i] = t;
  }

#pragma unroll
  for (int s = 0; s < 2; s++)
#pragma unroll
    for (int n = 0; n < 4; n++)
#pragma unroll
      for (int r = 0; r < 4; r++) {
        float v = po[s][n][r] / lsum[s*4 + r];
        AO[(size_t)(b*S_ + qw + s*16 + g*4 + r)*D_ + h*64 + n*16 + r16] = (bf16)v;
      }
}

// ---------------- fused residual + 2-partial reduce + LayerNorm ------------
template<bool XF32, bool OUTF32>
__global__ __launch_bounds__(256) void ln_res2(
    const void* __restrict__ xp, const float* __restrict__ p0,
    const float* __restrict__ p1, const float* __restrict__ sc,
    const float* __restrict__ bi, float* __restrict__ y,
    bf16* __restrict__ yb) {
  const int row = blockIdx.x, tid = threadIdx.x;
  const size_t base = (size_t)row * D_;
  float xv[4];
  if (XF32) {
    float4 a = ((const float4*)((const float*)xp + base))[tid];
    xv[0] = a.x; xv[1] = a.y; xv[2] = a.z; xv[3] = a.w;
  } else {
    bf16x4 a = ((const bf16x4*)((const bf16*)xp + base))[tid];
#pragma unroll
    for (int j = 0; j < 4; j++) xv[j] = (float)a[j];
  }
  float4 a0 = ((const float4*)(p0 + base))[tid];
  float4 a1 = ((const float4*)(p1 + base))[tid];
  float v[4] = {xv[0] + a0.x + a1.x, xv[1] + a0.y + a1.y,
                xv[2] + a0.z + a1.z, xv[3] + a0.w + a1.w};
  float s  = v[0] + v[1] + v[2] + v[3];
  float ss = v[0]*v[0] + v[1]*v[1] + v[2]*v[2] + v[3]*v[3];
#pragma unroll
  for (int off = 32; off >= 1; off >>= 1) {
    s  += __shfl_xor(s, off, 64);
    ss += __shfl_xor(ss, off, 64);
  }
  __shared__ float red[8];
  const int wv = tid >> 6;
  if ((tid & 63) == 0) { red[wv] = s; red[4 + wv] = ss; }
  __syncthreads();
  s  = red[0] + red[1] + red[2] + red[3];
  ss = red[4] + red[5] + red[6] + red[7];
  const float mu  = s * (1.0f / D_);
  const float inv = rsqrtf(ss * (1.0f / D_) - mu*mu + 1e-6f);
  float4 scv = ((const float4*)sc)[tid];
  float4 biv = ((const float4*)bi)[tid];
  float o[4];
  o[0] = (v[0]-mu)*inv*scv.x + biv.x;
  o[1] = (v[1]-mu)*inv*scv.y + biv.y;
  o[2] = (v[2]-mu)*inv*scv.z + biv.z;
  o[3] = (v[3]-mu)*inv*scv.w + biv.w;
  if (OUTF32) {
    ((float4*)(y + base))[tid] = make_float4(o[0], o[1], o[2], o[3]);
  } else {
    bf16x4 ob;
#pragma unroll
    for (int j = 0; j < 4; j++) ob[j] = (bf16)o[j];
    *(bf16x4*)&yb[base + tid*4] = ob;
  }
}

// ---------------- launch ----------------
extern "C" void kernel_launch(void* const* d_in, const int* in_sizes, int n_in,
                              void* d_out, int out_size, void* d_ws, size_t ws_size,
                              hipStream_t stream) {
  const float* X    = (const float*)d_in[0];
  const int*   mask = (const int*)d_in[1];
  const float* Wq   = (const float*)d_in[2];
  const float* bq   = (const float*)d_in[3];
  const float* Wk   = (const float*)d_in[4];
  const float* bk   = (const float*)d_in[5];
  const float* Wv   = (const float*)d_in[6];
  const float* bv   = (const float*)d_in[7];
  const float* Wo   = (const float*)d_in[8];
  const float* bo   = (const float*)d_in[9];
  const float* ln0s = (const float*)d_in[10];
  const float* ln0b = (const float*)d_in[11];
  const float* W1   = (const float*)d_in[12];
  const float* b1   = (const float*)d_in[13];
  const float* W2   = (const float*)d_in[14];
  const float* b2   = (const float*)d_in[15];
  const float* ln1s = (const float*)d_in[16];
  const float* ln1b = (const float*)d_in[17];
  float* out = (float*)d_out;

  // workspace layout (96 MB), lifetime-checked reuse:
  //  [0,8)    Xb -> AO -> X1b
  //  [8,16)   Wqkvt(6) + Wot(2)
  //  [16,24)  W1t   [24,32) W2t
  //  [32,64)  QKV(24)+Vt(8) -> FF1(32)
  //  [64,80)  bqkv+Mp (head) -> WoP0 -> F2P0
  //  [80,96)  WoP1 -> F2P1
  char* ws = (char*)d_ws;
  const size_t MB = 1024 * 1024;
  bf16*  Xb    = (bf16*)(ws + 0);        // 8MB
  bf16*  AO    = (bf16*)(ws + 0);        // reuse
  bf16*  X1b   = (bf16*)(ws + 0);        // reuse (AO dead after Wo gemm)
  bf16*  Wqkvt = (bf16*)(ws + 8*MB);     // 6MB  [3072][1024]
  bf16*  Wot   = (bf16*)(ws + 14*MB);    // 2MB  [1024][1024]
  bf16*  W1t   = (bf16*)(ws + 16*MB);    // 8MB  [4096][1024]
  bf16*  W2t   = (bf16*)(ws + 24*MB);    // 8MB  [1024][4096]
  bf16*  QKV   = (bf16*)(ws + 32*MB);    // 24MB [4096][3072]
  bf16*  Vt    = (bf16*)(ws + 56*MB);    // 8MB  [32][64][2048]
  bf16*  FF1   = (bf16*)(ws + 32*MB);    // 32MB reuse [4096][4096]
  float* P0    = (float*)(ws + 64*MB);   // 16MB partial 0 (Wo then FF2)
  float* P1    = (float*)(ws + 80*MB);   // 16MB partial 1
  float* bqkv  = (float*)(ws + 64*MB);   // 12KB head of P0 (dead by Wo gemm)
  float* Mp    = (float*)(ws + 64*MB + 16384);  // 16KB head of P0

  cast_f32_bf16<<<(M_*D_)/1024, 256, 0, stream>>>(X, Xb, M_*D_);
  copy3<<<12, 256, 0, stream>>>(bq, bk, bv, bqkv);
  prep_mask<<<16, 256, 0, stream>>>(mask, Mp);
  transpose_cast<<<dim3(D_/32, D_/32), 256, 0, stream>>>(Wq, Wqkvt, D_, D_);
  transpose_cast<<<dim3(D_/32, D_/32), 256, 0, stream>>>(Wk, Wqkvt + (size_t)1024*1024, D_, D_);
  transpose_cast<<<dim3(D_/32, D_/32), 256, 0, stream>>>(Wv, Wqkvt + (size_t)2048*1024, D_, D_);
  transpose_cast<<<dim3(D_/32, D_/32), 256, 0, stream>>>(Wo, Wot, D_, D_);
  transpose_cast<<<dim3(FF_/32, D_/32), 256, 0, stream>>>(W1, W1t, D_, FF_);
  transpose_cast<<<dim3(D_/32, FF_/32), 256, 0, stream>>>(W2, W2t, FF_, D_);

  gemm256<false><<<dim3(3072/256, M_/256), 512, 0, stream>>>(Xb, Wqkvt, bqkv, QKV, M_, 3072, D_);
  transpose_v<<<dim3(32, S_/64), 256, 0, stream>>>(QKV, Vt);
  attn<<<dim3(32, S_/128), 256, 0, stream>>>(QKV, Vt, Mp, AO);
  gemm_sk<2><<<dim3(D_/128, M_/128, 2), 256, 0, stream>>>(AO, Wot, bo, P0, M_, D_, D_);
  ln_res2<true,false><<<M_, 256, 0, stream>>>(X, P0, P1, ln0s, ln0b, nullptr, X1b);
  gemm256<true><<<dim3(FF_/256, M_/256), 512, 0, stream>>>(X1b, W1t, b1, FF1, M_, FF_, D_);
  gemm_sk<2><<<dim3(D_/128, M_/128, 2), 256, 0, stream>>>(FF1, W2t, b2, P0, M_, D_, FF_);
  ln_res2<false,true><<<M_, 256, 0, stream>>>(X1b, P0, P1, ln1s, ln1b, out, nullptr);
}